// Round 21
// baseline (222.366 us; speedup 1.0000x reference)
//
#include <hip/hip_runtime.h>
#include <hip/hip_bf16.h>
#include <math.h>

#define N_NODES 50000
#define N_EDGES 800000
#define E_TOT   (N_EDGES + N_NODES)   // 850000 (with self-loops)
#define IN_CH 128
#define HID 32
#define HEADS 8
#define OUT_CH 64
#define NEG_SLOPE 0.2f
#define NBLK 196                      // ceil(50000/256)
#define RBLK 3321                     // ceil(850000/256) rank blocks
#define G1BLK 3125                    // 50000/16 rows per MFMA block
#define G2BLK 782                     // ceil(50000/64)
#define ABLK 12500                    // 50000/4 nodes per 256-thread block
#define LOG2E 1.4426950408889634f

typedef __attribute__((ext_vector_type(8))) short bf16x8;
typedef __attribute__((ext_vector_type(4))) float f32x4;

__device__ __forceinline__ float lrelu(float x) { return x > 0.f ? x : NEG_SLOPE * x; }
// exp(lrelu(z)) = exp2(max(z*L, z*0.2L))  (branchless; valid since L>0)
__device__ __forceinline__ float explrelu(float z) {
    return exp2f(fmaxf(z * LOG2E, z * (NEG_SLOPE * LOG2E)));
}

__device__ __forceinline__ unsigned short f2bf(float f) {
    unsigned int u = __float_as_uint(f);
    unsigned int r = (u + 0x7FFFu + ((u >> 16) & 1u)) >> 16;   // round-nearest-even
    return (unsigned short)r;
}
__device__ __forceinline__ float bf2f(unsigned short u) {
    return __uint_as_float(((unsigned int)u) << 16);
}
__device__ __forceinline__ float bflo(unsigned int u) {       // low ushort -> float
    return __uint_as_float(u << 16);
}
__device__ __forceinline__ float bfhi(unsigned int u) {       // high ushort -> float
    return __uint_as_float(u & 0xFFFF0000u);
}

// ---------------- W1 transpose + bf16 cast: W1t[col][k] ----------------------
__global__ void w1cast_kernel(const float* __restrict__ W1,
                              unsigned short* __restrict__ W1t) {
    int i = blockIdx.x * 256 + threadIdx.x;    // 32768 elems
    int col = i >> 7, k = i & 127;
    W1t[i] = f2bf(W1[k * 256 + col]);
}

// ---------------- GEMM1 body (device fn, called from fused kernel) ----------
__device__ __forceinline__ void gemm1_body(
    int blk, int t,
    const float* __restrict__ x, const unsigned short* __restrict__ W1t,
    const float* __restrict__ att_s, const float* __restrict__ att_d,
    unsigned short* __restrict__ h1b, float* __restrict__ as1, float* __restrict__ ad1) {
    int lane = t & 63;
    int w = t >> 6;
    int lrow = lane & 15;
    int kg = lane >> 4;
    int row0 = blk * 16;
    int gr = row0 + lrow;                      // 3125*16 = 50000 exactly
    f32x4 acc0 = {0.f, 0.f, 0.f, 0.f};
    f32x4 acc1 = {0.f, 0.f, 0.f, 0.f};
    f32x4 acc2 = {0.f, 0.f, 0.f, 0.f};
    f32x4 acc3 = {0.f, 0.f, 0.f, 0.f};
#pragma unroll
    for (int ks = 0; ks < 4; ++ks) {
        const float* ap = &x[(size_t)gr * IN_CH + ks * 32 + kg * 8];
        float4 a0 = *(const float4*)ap;
        float4 a1 = *(const float4*)(ap + 4);
        union { bf16x8 v; unsigned int u[4]; } A;
        A.u[0] = ((unsigned)f2bf(a0.y) << 16) | f2bf(a0.x);
        A.u[1] = ((unsigned)f2bf(a0.w) << 16) | f2bf(a0.z);
        A.u[2] = ((unsigned)f2bf(a1.y) << 16) | f2bf(a1.x);
        A.u[3] = ((unsigned)f2bf(a1.w) << 16) | f2bf(a1.z);
        union { bf16x8 v; uint4 u; } B0, B1, B2, B3;
        int kb = ks * 32 + kg * 8;
        B0.u = *(const uint4*)&W1t[(size_t)(w * 64 + 0 * 16 + lrow) * IN_CH + kb];
        B1.u = *(const uint4*)&W1t[(size_t)(w * 64 + 1 * 16 + lrow) * IN_CH + kb];
        B2.u = *(const uint4*)&W1t[(size_t)(w * 64 + 2 * 16 + lrow) * IN_CH + kb];
        B3.u = *(const uint4*)&W1t[(size_t)(w * 64 + 3 * 16 + lrow) * IN_CH + kb];
        acc0 = __builtin_amdgcn_mfma_f32_16x16x32_bf16(A.v, B0.v, acc0, 0, 0, 0);
        acc1 = __builtin_amdgcn_mfma_f32_16x16x32_bf16(A.v, B1.v, acc1, 0, 0, 0);
        acc2 = __builtin_amdgcn_mfma_f32_16x16x32_bf16(A.v, B2.v, acc2, 0, 0, 0);
        acc3 = __builtin_amdgcn_mfma_f32_16x16x32_bf16(A.v, B3.v, acc3, 0, 0, 0);
    }
    float s0 = att_s[w * 64 + 0 * 16 + lrow], d0 = att_d[w * 64 + 0 * 16 + lrow];
    float s1 = att_s[w * 64 + 1 * 16 + lrow], d1 = att_d[w * 64 + 1 * 16 + lrow];
    float s2 = att_s[w * 64 + 2 * 16 + lrow], d2 = att_d[w * 64 + 2 * 16 + lrow];
    float s3 = att_s[w * 64 + 3 * 16 + lrow], d3 = att_d[w * 64 + 3 * 16 + lrow];
#pragma unroll
    for (int r = 0; r < 4; ++r) {
        int orow = row0 + kg * 4 + r;
        h1b[(size_t)orow * 256 + w * 64 +  0 + lrow] = f2bf(acc0[r]);
        h1b[(size_t)orow * 256 + w * 64 + 16 + lrow] = f2bf(acc1[r]);
        h1b[(size_t)orow * 256 + w * 64 + 32 + lrow] = f2bf(acc2[r]);
        h1b[(size_t)orow * 256 + w * 64 + 48 + lrow] = f2bf(acc3[r]);
        float p0 = acc0[r] * s0 + acc1[r] * s1;
        float q0 = acc0[r] * d0 + acc1[r] * d1;
        float p1 = acc2[r] * s2 + acc3[r] * s3;
        float q1 = acc2[r] * d2 + acc3[r] * d3;
        p0 += __shfl_xor(p0, 1); q0 += __shfl_xor(q0, 1);
        p1 += __shfl_xor(p1, 1); q1 += __shfl_xor(q1, 1);
        p0 += __shfl_xor(p0, 2); q0 += __shfl_xor(q0, 2);
        p1 += __shfl_xor(p1, 2); q1 += __shfl_xor(q1, 2);
        p0 += __shfl_xor(p0, 4); q0 += __shfl_xor(q0, 4);
        p1 += __shfl_xor(p1, 4); q1 += __shfl_xor(q1, 4);
        p0 += __shfl_xor(p0, 8); q0 += __shfl_xor(q0, 8);
        p1 += __shfl_xor(p1, 8); q1 += __shfl_xor(q1, 8);
        if (lrow == 0) {
            as1[orow * HEADS + 2 * w]     = p0;
            ad1[orow * HEADS + 2 * w]     = q0;
            as1[orow * HEADS + 2 * w + 1] = p1;
            ad1[orow * HEADS + 2 * w + 1] = q1;
        }
    }
}

// ---------------- Fused phase 1: rank (8-replica counters) + gemm1 + w2cast -
// Replica r = e&7 splits each node's ~17 same-address atomics across 8
// independent counters -> 8x less same-address serialization.
__global__ __launch_bounds__(256) void fused1_kernel(
    const int* __restrict__ ei, int* __restrict__ deg8, int* __restrict__ rank,
    const float* __restrict__ x, const unsigned short* __restrict__ W1t,
    const float* __restrict__ att_s, const float* __restrict__ att_d,
    unsigned short* __restrict__ h1b, float* __restrict__ as1, float* __restrict__ ad1,
    const float* __restrict__ W2, unsigned short* __restrict__ W2t) {
    int b = blockIdx.x;
    if (b < RBLK) {
        int e = b * 256 + threadIdx.x;
        if (e < E_TOT) {
            int d = (e < N_EDGES) ? ei[N_EDGES + e] : (e - N_EDGES);
            int r = e & 7;
            rank[e] = atomicAdd(&deg8[r * N_NODES + d], 1);
        }
    } else if (b < RBLK + G1BLK) {
        gemm1_body(b - RBLK, threadIdx.x, x, W1t, att_s, att_d, h1b, as1, ad1);
    } else {
        int i = (b - RBLK - G1BLK) * 256 + threadIdx.x;   // 16384 elems, 64 blocks
        int col = i >> 8, k = i & 255;
        W2t[i] = f2bf(W2[k * 64 + col]);
    }
}

// scan1: per-node total over 8 replicas; overwrite deg8 with per-replica
// exclusive prefix (pref[r][g] = sum of replicas < r); block-local scan of totals.
__global__ void scan1_kernel(int* __restrict__ deg8, int* __restrict__ off,
                             int* __restrict__ bsum) {
    __shared__ int s[256];
    int b = blockIdx.x, t = threadIdx.x, g = b * 256 + t;
    int v = 0;
    if (g < N_NODES) {
        int run = 0;
#pragma unroll
        for (int r = 0; r < 8; ++r) {
            int c = deg8[r * N_NODES + g];
            deg8[r * N_NODES + g] = run;
            run += c;
        }
        v = run;
    }
    s[t] = v;
    __syncthreads();
    for (int d = 1; d < 256; d <<= 1) {
        int o = (t >= d) ? s[t - d] : 0;
        __syncthreads();
        s[t] += o;
        __syncthreads();
    }
    if (g < N_NODES) off[g] = s[t] - v;
    if (t == 255) bsum[b] = s[t];
}

__global__ void scan2_kernel(int* __restrict__ bsum, int nb) {
    __shared__ int s[256];
    int t = threadIdx.x;
    int v = (t < nb) ? bsum[t] : 0;
    s[t] = v;
    __syncthreads();
    for (int d = 1; d < 256; d <<= 1) {
        int o = (t >= d) ? s[t - d] : 0;
        __syncthreads();
        s[t] += o;
        __syncthreads();
    }
    if (t < nb) bsum[t] = s[t] - v;
}

__global__ void scan3_kernel(int* __restrict__ off, const int* __restrict__ bsum) {
    int b = blockIdx.x, t = threadIdx.x, g = b * 256 + t;
    if (g < N_NODES) off[g] += bsum[b];
    if (g == 0) off[N_NODES] = E_TOT;
}

// place_kernel: non-atomic placement: off[d] + replica prefix + in-replica rank.
__global__ void place_kernel(const int* __restrict__ ei, const int* __restrict__ off,
                             const int* __restrict__ deg8, const int* __restrict__ rank,
                             int* __restrict__ ssrc) {
    int e = blockIdx.x * blockDim.x + threadIdx.x;
    if (e >= E_TOT) return;
    int s, d;
    if (e < N_EDGES) { s = ei[e]; d = ei[N_EDGES + e]; }
    else             { s = d = e - N_EDGES; }
    int r = e & 7;
    ssrc[off[d] + deg8[r * N_NODES + d] + rank[e]] = s;
}

// ---------------- Aggregate layer 1: dual-edge wide gathers, 2-deep pipe ----
__global__ __launch_bounds__(256) void agg1_kernel(
    const int* __restrict__ off, const int* __restrict__ ssrc,
    const unsigned short* __restrict__ h1b, const float* __restrict__ as1,
    const float* __restrict__ ad1, const float* __restrict__ b1,
    unsigned short* __restrict__ houtb) {
    int t = threadIdx.x;
    int lane = t & 63;
    int n = blockIdx.x * 4 + (t >> 6);
    int h    = lane >> 3;     // weight-phase head
    int e8   = lane & 7;      // weight-phase edge slot
    int c    = lane & 31;     // channel group: ushorts [c*8, c*8+8)
    int hh   = c >> 2;        // head of my channel group
    int half = lane >> 5;     // 0: even edges, 1: odd edges
    int start = off[n], end = off[n + 1];
    int last = end - 1;
    float ad_w = ad1[n * HEADS + e8];
    float acc[8];
#pragma unroll
    for (int j = 0; j < 8; ++j) acc[j] = 0.f;
    float den = 0.f;
    int sv = ssrc[min(start + e8, last)];
    int se = __shfl(sv, h);
    float av = as1[se * HEADS + e8];
    const unsigned short* base = h1b + c * 8;
    uint4 g0 = *(const uint4*)&base[(unsigned)__shfl(sv, 0 + half) * 256];
    uint4 g1 = *(const uint4*)&base[(unsigned)__shfl(sv, 2 + half) * 256];
    uint4 g2 = *(const uint4*)&base[(unsigned)__shfl(sv, 4 + half) * 256];
    uint4 g3 = *(const uint4*)&base[(unsigned)__shfl(sv, 6 + half) * 256];
    for (int i = start; i < end; i += 8) {
        int inext = i + 8;
        int sv_n = ssrc[min(inext + e8, last)];
        int se_n = __shfl(sv_n, h);
        float av_n = as1[se_n * HEADS + e8];
        uint4 n0 = *(const uint4*)&base[(unsigned)__shfl(sv_n, 0 + half) * 256];
        uint4 n1 = *(const uint4*)&base[(unsigned)__shfl(sv_n, 2 + half) * 256];
        uint4 n2 = *(const uint4*)&base[(unsigned)__shfl(sv_n, 4 + half) * 256];
        uint4 n3 = *(const uint4*)&base[(unsigned)__shfl(sv_n, 6 + half) * 256];
        float wv = explrelu(av + ad_w);
        float w0 = __shfl(wv, (0 + half) * 8 + hh);
        float w1 = __shfl(wv, (2 + half) * 8 + hh);
        float w2 = __shfl(wv, (4 + half) * 8 + hh);
        float w3 = __shfl(wv, (6 + half) * 8 + hh);
        w0 = (i + 0 + half < end) ? w0 : 0.f;
        w1 = (i + 2 + half < end) ? w1 : 0.f;
        w2 = (i + 4 + half < end) ? w2 : 0.f;
        w3 = (i + 6 + half < end) ? w3 : 0.f;
        den += w0 + w1 + w2 + w3;
        acc[0] = fmaf(w0, bflo(g0.x), acc[0]); acc[1] = fmaf(w0, bfhi(g0.x), acc[1]);
        acc[2] = fmaf(w0, bflo(g0.y), acc[2]); acc[3] = fmaf(w0, bfhi(g0.y), acc[3]);
        acc[4] = fmaf(w0, bflo(g0.z), acc[4]); acc[5] = fmaf(w0, bfhi(g0.z), acc[5]);
        acc[6] = fmaf(w0, bflo(g0.w), acc[6]); acc[7] = fmaf(w0, bfhi(g0.w), acc[7]);
        acc[0] = fmaf(w1, bflo(g1.x), acc[0]); acc[1] = fmaf(w1, bfhi(g1.x), acc[1]);
        acc[2] = fmaf(w1, bflo(g1.y), acc[2]); acc[3] = fmaf(w1, bfhi(g1.y), acc[3]);
        acc[4] = fmaf(w1, bflo(g1.z), acc[4]); acc[5] = fmaf(w1, bfhi(g1.z), acc[5]);
        acc[6] = fmaf(w1, bflo(g1.w), acc[6]); acc[7] = fmaf(w1, bfhi(g1.w), acc[7]);
        acc[0] = fmaf(w2, bflo(g2.x), acc[0]); acc[1] = fmaf(w2, bfhi(g2.x), acc[1]);
        acc[2] = fmaf(w2, bflo(g2.y), acc[2]); acc[3] = fmaf(w2, bfhi(g2.y), acc[3]);
        acc[4] = fmaf(w2, bflo(g2.z), acc[4]); acc[5] = fmaf(w2, bfhi(g2.z), acc[5]);
        acc[6] = fmaf(w2, bflo(g2.w), acc[6]); acc[7] = fmaf(w2, bfhi(g2.w), acc[7]);
        acc[0] = fmaf(w3, bflo(g3.x), acc[0]); acc[1] = fmaf(w3, bfhi(g3.x), acc[1]);
        acc[2] = fmaf(w3, bflo(g3.y), acc[2]); acc[3] = fmaf(w3, bfhi(g3.y), acc[3]);
        acc[4] = fmaf(w3, bflo(g3.z), acc[4]); acc[5] = fmaf(w3, bfhi(g3.z), acc[5]);
        acc[6] = fmaf(w3, bflo(g3.w), acc[6]); acc[7] = fmaf(w3, bfhi(g3.w), acc[7]);
        g0 = n0; g1 = n1; g2 = n2; g3 = n3;
        sv = sv_n; av = av_n;
    }
#pragma unroll
    for (int j = 0; j < 8; ++j) acc[j] += __shfl_xor(acc[j], 32);
    den += __shfl_xor(den, 32);
    if (lane < 32) {
        float r = __builtin_amdgcn_rcpf(den);
        float4 b0 = *(const float4*)&b1[c * 8];
        float4 b4 = *(const float4*)&b1[c * 8 + 4];
        float v0 = fmaf(acc[0], r, b0.x);
        float v1 = fmaf(acc[1], r, b0.y);
        float v2 = fmaf(acc[2], r, b0.z);
        float v3 = fmaf(acc[3], r, b0.w);
        float v4 = fmaf(acc[4], r, b4.x);
        float v5 = fmaf(acc[5], r, b4.y);
        float v6 = fmaf(acc[6], r, b4.z);
        float v7 = fmaf(acc[7], r, b4.w);
        v0 = v0 > 0.f ? v0 : expm1f(v0);
        v1 = v1 > 0.f ? v1 : expm1f(v1);
        v2 = v2 > 0.f ? v2 : expm1f(v2);
        v3 = v3 > 0.f ? v3 : expm1f(v3);
        v4 = v4 > 0.f ? v4 : expm1f(v4);
        v5 = v5 > 0.f ? v5 : expm1f(v5);
        v6 = v6 > 0.f ? v6 : expm1f(v6);
        v7 = v7 > 0.f ? v7 : expm1f(v7);
        uint4 ob;
        ob.x = (unsigned)f2bf(v0) | ((unsigned)f2bf(v1) << 16);
        ob.y = (unsigned)f2bf(v2) | ((unsigned)f2bf(v3) << 16);
        ob.z = (unsigned)f2bf(v4) | ((unsigned)f2bf(v5) << 16);
        ob.w = (unsigned)f2bf(v6) | ((unsigned)f2bf(v7) << 16);
        *(uint4*)&houtb[(unsigned)n * 256 + c * 8] = ob;
    }
}

// ---------------- GEMM2 via MFMA (bf16 in, fp32 acc) + alpha epilogue -------
__global__ __launch_bounds__(256) void gemm2_mfma(
    const unsigned short* __restrict__ hinb, const unsigned short* __restrict__ W2t,
    const float* __restrict__ att_s2, const float* __restrict__ att_d2,
    unsigned short* __restrict__ h2b, float* __restrict__ as2, float* __restrict__ ad2) {
    int t = threadIdx.x;
    int lane = t & 63;
    int w = t >> 6;
    int lrow = lane & 15;
    int kg = lane >> 4;
    int row0 = blockIdx.x * 64 + w * 16;
    int gr = min(row0 + lrow, N_NODES - 1);    // clamp loads (last block partial)
    f32x4 acc0 = {0.f, 0.f, 0.f, 0.f};
    f32x4 acc1 = {0.f, 0.f, 0.f, 0.f};
    f32x4 acc2 = {0.f, 0.f, 0.f, 0.f};
    f32x4 acc3 = {0.f, 0.f, 0.f, 0.f};
#pragma unroll
    for (int ks = 0; ks < 8; ++ks) {
        int kb = ks * 32 + kg * 8;
        union { bf16x8 v; uint4 u; } A, B0, B1, B2, B3;
        A.u  = *(const uint4*)&hinb[(size_t)gr * 256 + kb];
        B0.u = *(const uint4*)&W2t[(size_t)(0 * 16 + lrow) * 256 + kb];
        B1.u = *(const uint4*)&W2t[(size_t)(1 * 16 + lrow) * 256 + kb];
        B2.u = *(const uint4*)&W2t[(size_t)(2 * 16 + lrow) * 256 + kb];
        B3.u = *(const uint4*)&W2t[(size_t)(3 * 16 + lrow) * 256 + kb];
        acc0 = __builtin_amdgcn_mfma_f32_16x16x32_bf16(A.v, B0.v, acc0, 0, 0, 0);
        acc1 = __builtin_amdgcn_mfma_f32_16x16x32_bf16(A.v, B1.v, acc1, 0, 0, 0);
        acc2 = __builtin_amdgcn_mfma_f32_16x16x32_bf16(A.v, B2.v, acc2, 0, 0, 0);
        acc3 = __builtin_amdgcn_mfma_f32_16x16x32_bf16(A.v, B3.v, acc3, 0, 0, 0);
    }
    float s0 = att_s2[ 0 + lrow], d0 = att_d2[ 0 + lrow];
    float s1 = att_s2[16 + lrow], d1 = att_d2[16 + lrow];
    float s2 = att_s2[32 + lrow], d2 = att_d2[32 + lrow];
    float s3 = att_s2[48 + lrow], d3 = att_d2[48 + lrow];
#pragma unroll
    for (int r = 0; r < 4; ++r) {
        int orow = row0 + kg * 4 + r;
        float p = acc0[r] * s0 + acc1[r] * s1 + acc2[r] * s2 + acc3[r] * s3;
        float q = acc0[r] * d0 + acc1[r] * d1 + acc2[r] * d2 + acc3[r] * d3;
        p += __shfl_xor(p, 1); q += __shfl_xor(q, 1);
        p += __shfl_xor(p, 2); q += __shfl_xor(q, 2);
        p += __shfl_xor(p, 4); q += __shfl_xor(q, 4);
        p += __shfl_xor(p, 8); q += __shfl_xor(q, 8);
        if (orow < N_NODES) {
            h2b[(size_t)orow * 64 +  0 + lrow] = f2bf(acc0[r]);
            h2b[(size_t)orow * 64 + 16 + lrow] = f2bf(acc1[r]);
            h2b[(size_t)orow * 64 + 32 + lrow] = f2bf(acc2[r]);
            h2b[(size_t)orow * 64 + 48 + lrow] = f2bf(acc3[r]);
            if (lrow == 0) { as2[orow] = p; ad2[orow] = q; }
        }
    }
}

// ---------------- Aggregate layer 2: quad-edge wide gathers -----------------
__global__ __launch_bounds__(256) void agg2_kernel(
    const int* __restrict__ off, const int* __restrict__ ssrc,
    const unsigned short* __restrict__ h2b, const float* __restrict__ as2,
    const float* __restrict__ ad2, const float* __restrict__ b2,
    float* __restrict__ out) {
    int t = threadIdx.x;
    int lane = t & 63;
    int e8 = lane & 7;
    int q = lane & 15;
    int quarter = lane >> 4;
    int n = blockIdx.x * 4 + (t >> 6);
    int start = off[n], end = off[n + 1];
    int last = end - 1;
    float adv = ad2[n];
    float acc[4];
#pragma unroll
    for (int j = 0; j < 4; ++j) acc[j] = 0.f;
    float den = 0.f;
    int sv = ssrc[min(start + e8, last)];
    float av = as2[sv];
    for (int i = start; i < end; i += 8) {
        int inext = i + 8;
        int sv_n = ssrc[min(inext + e8, last)];
        float av_n = as2[sv_n];
        float wv = explrelu(av + adv);
#pragma unroll
        for (int k = 0; k < 2; ++k) {
            int me = 4 * k + quarter;
            float wj = __shfl(wv, me);
            int   sj = __shfl(sv, me);
            wj = (i + me < end) ? wj : 0.f;
            uint2 u = *(const uint2*)&h2b[(unsigned)sj * 64 + q * 4];
            den += wj;
            acc[0] = fmaf(wj, bflo(u.x), acc[0]);
            acc[1] = fmaf(wj, bfhi(u.x), acc[1]);
            acc[2] = fmaf(wj, bflo(u.y), acc[2]);
            acc[3] = fmaf(wj, bfhi(u.y), acc[3]);
        }
        sv = sv_n; av = av_n;
    }
#pragma unroll
    for (int j = 0; j < 4; ++j) {
        acc[j] += __shfl_xor(acc[j], 16);
        acc[j] += __shfl_xor(acc[j], 32);
    }
    den += __shfl_xor(den, 16);
    den += __shfl_xor(den, 32);
    if (lane < 16) {
        float r = __builtin_amdgcn_rcpf(den);
        float4 bv = *(const float4*)&b2[q * 4];
        float4 o;
        o.x = fmaf(acc[0], r, bv.x);
        o.y = fmaf(acc[1], r, bv.y);
        o.z = fmaf(acc[2], r, bv.z);
        o.w = fmaf(acc[3], r, bv.w);
        *(float4*)&out[(unsigned)n * 64 + q * 4] = o;
    }
}

extern "C" void kernel_launch(void* const* d_in, const int* in_sizes, int n_in,
                              void* d_out, int out_size, void* d_ws, size_t ws_size,
                              hipStream_t stream) {
    const float* x    = (const float*)d_in[0];
    const int*   ei   = (const int*)d_in[1];
    const float* W1   = (const float*)d_in[2];
    const float* ats1 = (const float*)d_in[3];
    const float* atd1 = (const float*)d_in[4];
    const float* b1   = (const float*)d_in[5];
    const float* W2   = (const float*)d_in[6];
    const float* ats2 = (const float*)d_in[7];
    const float* atd2 = (const float*)d_in[8];
    const float* b2   = (const float*)d_in[9];
    float* out = (float*)d_out;

    char* ws = (char*)d_ws;
    size_t o = 0;
    auto alloc = [&](size_t bytes) { size_t r = o; o = (o + bytes + 255) & ~255UL; return r; };
    unsigned short* h1b   = (unsigned short*)(ws + alloc((size_t)N_NODES * 256 * 2));
    unsigned short* h2inb = (unsigned short*)(ws + alloc((size_t)N_NODES * 256 * 2));
    unsigned short* h2b   = (unsigned short*)(ws + alloc((size_t)N_NODES * 64 * 2));
    unsigned short* W1t   = (unsigned short*)(ws + alloc((size_t)256 * 128 * 2));
    unsigned short* W2t   = (unsigned short*)(ws + alloc((size_t)64 * 256 * 2));
    float* as1  = (float*)(ws + alloc((size_t)N_NODES * HEADS * 4));
    float* ad1  = (float*)(ws + alloc((size_t)N_NODES * HEADS * 4));
    float* as2  = (float*)(ws + alloc((size_t)N_NODES * 4));
    float* ad2  = (float*)(ws + alloc((size_t)N_NODES * 4));
    int*   deg8 = (int*)(ws + alloc((size_t)N_NODES * 8 * 4));   // 8 replicas
    int*   off  = (int*)(ws + alloc((size_t)(N_NODES + 1) * 4));
    int*   bsum = (int*)(ws + alloc(256 * 4));
    int*   rank = (int*)(ws + alloc((size_t)E_TOT * 4));
    int*   ssrc = (int*)(ws + alloc((size_t)E_TOT * 4));

    (void)hipMemsetAsync(deg8, 0, (size_t)N_NODES * 8 * 4, stream);
    int eblk = (E_TOT + 255) / 256;

    w1cast_kernel<<<128, 256, 0, stream>>>(W1, W1t);
    fused1_kernel<<<RBLK + G1BLK + 64, 256, 0, stream>>>(
        ei, deg8, rank, x, W1t, ats1, atd1, h1b, as1, ad1, W2, W2t);
    scan1_kernel<<<NBLK, 256, 0, stream>>>(deg8, off, bsum);
    scan2_kernel<<<1, 256, 0, stream>>>(bsum, NBLK);
    scan3_kernel<<<NBLK, 256, 0, stream>>>(off, bsum);
    place_kernel<<<eblk, 256, 0, stream>>>(ei, off, deg8, rank, ssrc);

    agg1_kernel<<<ABLK, 256, 0, stream>>>(off, ssrc, h1b, as1, ad1, b1, h2inb);

    gemm2_mfma<<<G2BLK, 256, 0, stream>>>(h2inb, W2t, ats2, atd2, h2b, as2, ad2);
    agg2_kernel<<<ABLK, 256, 0, stream>>>(off, ssrc, h2b, as2, ad2, b2, out);
}

// Round 22
// 206.112 us; speedup vs baseline: 1.0789x; 1.0789x over previous
//
#include <hip/hip_runtime.h>
#include <hip/hip_bf16.h>
#include <math.h>

#define N_NODES 50000
#define N_EDGES 800000
#define E_TOT   (N_EDGES + N_NODES)   // 850000 (with self-loops)
#define IN_CH 128
#define HID 32
#define HEADS 8
#define OUT_CH 64
#define NEG_SLOPE 0.2f
#define G1BLK 3125                    // 50000/16 rows per MFMA block
#define G2BLK 782                     // ceil(50000/64)
#define ABLK 12500                    // 50000/4 nodes per 256-thread block
#define LOG2E 1.4426950408889634f

// ---- atomic-free CSR build geometry ----
#define CHUNK_E 5376                  // 21 edges/thread * 256
#define NCHUNK 159                    // ceil(850000/5376)
#define NBUCK 391                     // dst>>7, max 49999>>7 = 390
#define CNT_TOT (NBUCK * NCHUNK)      // 62169
#define SBLK 243                      // ceil(62169/256)

typedef __attribute__((ext_vector_type(8))) short bf16x8;
typedef __attribute__((ext_vector_type(4))) float f32x4;

__device__ __forceinline__ float explrelu(float z) {
    return exp2f(fmaxf(z * LOG2E, z * (NEG_SLOPE * LOG2E)));
}

__device__ __forceinline__ unsigned short f2bf(float f) {
    unsigned int u = __float_as_uint(f);
    unsigned int r = (u + 0x7FFFu + ((u >> 16) & 1u)) >> 16;   // round-nearest-even
    return (unsigned short)r;
}
__device__ __forceinline__ float bf2f(unsigned short u) {
    return __uint_as_float(((unsigned int)u) << 16);
}
__device__ __forceinline__ float bflo(unsigned int u) {
    return __uint_as_float(u << 16);
}
__device__ __forceinline__ float bfhi(unsigned int u) {
    return __uint_as_float(u & 0xFFFF0000u);
}

// ---------------- sort level 1: per-chunk bucket histogram (LDS only) -------
__global__ __launch_bounds__(256) void hist1_kernel(const int* __restrict__ ei,
                                                    int* __restrict__ cnt) {
    __shared__ int hist[NBUCK];
    int t = threadIdx.x, blk = blockIdx.x;
    for (int j = t; j < NBUCK; j += 256) hist[j] = 0;
    __syncthreads();
#pragma unroll
    for (int i = 0; i < 21; ++i) {
        int e = blk * CHUNK_E + i * 256 + t;
        if (e < E_TOT) {
            int d = (e < N_EDGES) ? ei[N_EDGES + e] : (e - N_EDGES);
            atomicAdd(&hist[d >> 7], 1);
        }
    }
    __syncthreads();
    for (int j = t; j < NBUCK; j += 256) cnt[j * NCHUNK + blk] = hist[j];
}

// ---------------- scan of cnt (bucket-major), 3-kernel pattern --------------
__global__ void sscan1_kernel(const int* __restrict__ cnt, int* __restrict__ pos,
                              int* __restrict__ bsum) {
    __shared__ int s[256];
    int b = blockIdx.x, t = threadIdx.x, g = b * 256 + t;
    int v = (g < CNT_TOT) ? cnt[g] : 0;
    s[t] = v;
    __syncthreads();
    for (int d = 1; d < 256; d <<= 1) {
        int o = (t >= d) ? s[t - d] : 0;
        __syncthreads();
        s[t] += o;
        __syncthreads();
    }
    if (g < CNT_TOT) pos[g] = s[t] - v;
    if (t == 255) bsum[b] = s[t];
}

__global__ void sscan2_kernel(int* __restrict__ bsum, int nb) {
    __shared__ int s[256];
    int t = threadIdx.x;
    int v = (t < nb) ? bsum[t] : 0;
    s[t] = v;
    __syncthreads();
    for (int d = 1; d < 256; d <<= 1) {
        int o = (t >= d) ? s[t - d] : 0;
        __syncthreads();
        s[t] += o;
        __syncthreads();
    }
    if (t < nb) bsum[t] = s[t] - v;
}

__global__ void sscan3_kernel(int* __restrict__ pos, const int* __restrict__ bsum) {
    int b = blockIdx.x, t = threadIdx.x, g = b * 256 + t;
    if (g < CNT_TOT) pos[g] += bsum[b];
}

// ---------------- sort level 1 scatter: bucket-grouped tmp arrays -----------
__global__ __launch_bounds__(256) void scat1_kernel(const int* __restrict__ ei,
                                                    const int* __restrict__ pos,
                                                    int* __restrict__ tmp_s,
                                                    int* __restrict__ tmp_d) {
    __shared__ int cur[NBUCK];
    int t = threadIdx.x, blk = blockIdx.x;
    for (int j = t; j < NBUCK; j += 256) cur[j] = pos[j * NCHUNK + blk];
    __syncthreads();
#pragma unroll
    for (int i = 0; i < 21; ++i) {
        int e = blk * CHUNK_E + i * 256 + t;
        if (e < E_TOT) {
            int s, d;
            if (e < N_EDGES) { s = ei[e]; d = ei[N_EDGES + e]; }
            else             { s = d = e - N_EDGES; }
            int p = atomicAdd(&cur[d >> 7], 1);   // LDS atomic
            tmp_s[p] = s;
            tmp_d[p] = d;
        }
    }
}

// ---------------- sort level 2: per-bucket node grouping + off[] ------------
__global__ __launch_bounds__(256) void l2group_kernel(
    const int* __restrict__ pos, const int* __restrict__ tmp_s,
    const int* __restrict__ tmp_d, int* __restrict__ off, int* __restrict__ ssrc) {
    __shared__ int nc[128];
    __shared__ int sc[128];
    int b = blockIdx.x, t = threadIdx.x;
    int seg_start = pos[b * NCHUNK];
    int seg_end = (b + 1 < NBUCK) ? pos[(b + 1) * NCHUNK] : E_TOT;
    if (t < 128) nc[t] = 0;
    __syncthreads();
    for (int i = seg_start + t; i < seg_end; i += 256)
        atomicAdd(&nc[tmp_d[i] & 127], 1);
    __syncthreads();
    if (t < 128) sc[t] = nc[t];
    __syncthreads();
    for (int dd = 1; dd < 128; dd <<= 1) {
        int v = 0;
        if (t < 128 && t >= dd) v = sc[t - dd];
        __syncthreads();
        if (t < 128) sc[t] += v;
        __syncthreads();
    }
    if (t < 128) {
        int excl = sc[t] - nc[t];
        int node = b * 128 + t;
        if (node < N_NODES) off[node] = seg_start + excl;
        nc[t] = seg_start + excl;                 // reuse as cursor
    }
    if (b == 0 && t == 0) off[N_NODES] = E_TOT;
    __syncthreads();
    for (int i = seg_start + t; i < seg_end; i += 256) {
        int d = tmp_d[i];
        int p = atomicAdd(&nc[d & 127], 1);       // LDS atomic
        ssrc[p] = tmp_s[i];
    }
}

// ---------------- W1 transpose + bf16 cast: W1t[col][k] ----------------------
__global__ void w1cast_kernel(const float* __restrict__ W1,
                              unsigned short* __restrict__ W1t) {
    int i = blockIdx.x * 256 + threadIdx.x;    // 32768 elems
    int col = i >> 7, k = i & 127;
    W1t[i] = f2bf(W1[k * 256 + col]);
}

// ---------------- W2 transpose + bf16 cast: W2t[col][k] ----------------------
__global__ void w2cast_kernel(const float* __restrict__ W2,
                              unsigned short* __restrict__ W2t) {
    int i = blockIdx.x * 256 + threadIdx.x;    // 16384 elems
    int col = i >> 8, k = i & 255;
    W2t[i] = f2bf(W2[k * 64 + col]);
}

// ---------------- GEMM1 via MFMA (bf16 in, fp32 acc) + alpha epilogue -------
__global__ __launch_bounds__(256) void gemm1_mfma(
    const float* __restrict__ x, const unsigned short* __restrict__ W1t,
    const float* __restrict__ att_s, const float* __restrict__ att_d,
    unsigned short* __restrict__ h1b, float* __restrict__ as1, float* __restrict__ ad1) {
    int t = threadIdx.x;
    int lane = t & 63;
    int w = t >> 6;
    int lrow = lane & 15;
    int kg = lane >> 4;
    int row0 = blockIdx.x * 16;
    int gr = row0 + lrow;                      // 3125*16 = 50000 exactly
    f32x4 acc0 = {0.f, 0.f, 0.f, 0.f};
    f32x4 acc1 = {0.f, 0.f, 0.f, 0.f};
    f32x4 acc2 = {0.f, 0.f, 0.f, 0.f};
    f32x4 acc3 = {0.f, 0.f, 0.f, 0.f};
#pragma unroll
    for (int ks = 0; ks < 4; ++ks) {
        const float* ap = &x[(size_t)gr * IN_CH + ks * 32 + kg * 8];
        float4 a0 = *(const float4*)ap;
        float4 a1 = *(const float4*)(ap + 4);
        union { bf16x8 v; unsigned int u[4]; } A;
        A.u[0] = ((unsigned)f2bf(a0.y) << 16) | f2bf(a0.x);
        A.u[1] = ((unsigned)f2bf(a0.w) << 16) | f2bf(a0.z);
        A.u[2] = ((unsigned)f2bf(a1.y) << 16) | f2bf(a1.x);
        A.u[3] = ((unsigned)f2bf(a1.w) << 16) | f2bf(a1.z);
        union { bf16x8 v; uint4 u; } B0, B1, B2, B3;
        int kb = ks * 32 + kg * 8;
        B0.u = *(const uint4*)&W1t[(size_t)(w * 64 + 0 * 16 + lrow) * IN_CH + kb];
        B1.u = *(const uint4*)&W1t[(size_t)(w * 64 + 1 * 16 + lrow) * IN_CH + kb];
        B2.u = *(const uint4*)&W1t[(size_t)(w * 64 + 2 * 16 + lrow) * IN_CH + kb];
        B3.u = *(const uint4*)&W1t[(size_t)(w * 64 + 3 * 16 + lrow) * IN_CH + kb];
        acc0 = __builtin_amdgcn_mfma_f32_16x16x32_bf16(A.v, B0.v, acc0, 0, 0, 0);
        acc1 = __builtin_amdgcn_mfma_f32_16x16x32_bf16(A.v, B1.v, acc1, 0, 0, 0);
        acc2 = __builtin_amdgcn_mfma_f32_16x16x32_bf16(A.v, B2.v, acc2, 0, 0, 0);
        acc3 = __builtin_amdgcn_mfma_f32_16x16x32_bf16(A.v, B3.v, acc3, 0, 0, 0);
    }
    float s0 = att_s[w * 64 + 0 * 16 + lrow], d0 = att_d[w * 64 + 0 * 16 + lrow];
    float s1 = att_s[w * 64 + 1 * 16 + lrow], d1 = att_d[w * 64 + 1 * 16 + lrow];
    float s2 = att_s[w * 64 + 2 * 16 + lrow], d2 = att_d[w * 64 + 2 * 16 + lrow];
    float s3 = att_s[w * 64 + 3 * 16 + lrow], d3 = att_d[w * 64 + 3 * 16 + lrow];
#pragma unroll
    for (int r = 0; r < 4; ++r) {
        int orow = row0 + kg * 4 + r;
        h1b[(size_t)orow * 256 + w * 64 +  0 + lrow] = f2bf(acc0[r]);
        h1b[(size_t)orow * 256 + w * 64 + 16 + lrow] = f2bf(acc1[r]);
        h1b[(size_t)orow * 256 + w * 64 + 32 + lrow] = f2bf(acc2[r]);
        h1b[(size_t)orow * 256 + w * 64 + 48 + lrow] = f2bf(acc3[r]);
        float p0 = acc0[r] * s0 + acc1[r] * s1;
        float q0 = acc0[r] * d0 + acc1[r] * d1;
        float p1 = acc2[r] * s2 + acc3[r] * s3;
        float q1 = acc2[r] * d2 + acc3[r] * d3;
        p0 += __shfl_xor(p0, 1); q0 += __shfl_xor(q0, 1);
        p1 += __shfl_xor(p1, 1); q1 += __shfl_xor(q1, 1);
        p0 += __shfl_xor(p0, 2); q0 += __shfl_xor(q0, 2);
        p1 += __shfl_xor(p1, 2); q1 += __shfl_xor(q1, 2);
        p0 += __shfl_xor(p0, 4); q0 += __shfl_xor(q0, 4);
        p1 += __shfl_xor(p1, 4); q1 += __shfl_xor(q1, 4);
        p0 += __shfl_xor(p0, 8); q0 += __shfl_xor(q0, 8);
        p1 += __shfl_xor(p1, 8); q1 += __shfl_xor(q1, 8);
        if (lrow == 0) {
            as1[orow * HEADS + 2 * w]     = p0;
            ad1[orow * HEADS + 2 * w]     = q0;
            as1[orow * HEADS + 2 * w + 1] = p1;
            ad1[orow * HEADS + 2 * w + 1] = q1;
        }
    }
}

// ---------------- Aggregate layer 1: dual-edge wide gathers, 2-deep pipe ----
__global__ __launch_bounds__(256) void agg1_kernel(
    const int* __restrict__ off, const int* __restrict__ ssrc,
    const unsigned short* __restrict__ h1b, const float* __restrict__ as1,
    const float* __restrict__ ad1, const float* __restrict__ b1,
    unsigned short* __restrict__ houtb) {
    int t = threadIdx.x;
    int lane = t & 63;
    int n = blockIdx.x * 4 + (t >> 6);
    int h    = lane >> 3;     // weight-phase head
    int e8   = lane & 7;      // weight-phase edge slot
    int c    = lane & 31;     // channel group: ushorts [c*8, c*8+8)
    int hh   = c >> 2;        // head of my channel group
    int half = lane >> 5;     // 0: even edges, 1: odd edges
    int start = off[n], end = off[n + 1];
    int last = end - 1;
    float ad_w = ad1[n * HEADS + e8];
    float acc[8];
#pragma unroll
    for (int j = 0; j < 8; ++j) acc[j] = 0.f;
    float den = 0.f;
    int sv = ssrc[min(start + e8, last)];
    int se = __shfl(sv, h);
    float av = as1[se * HEADS + e8];
    const unsigned short* base = h1b + c * 8;
    uint4 g0 = *(const uint4*)&base[(unsigned)__shfl(sv, 0 + half) * 256];
    uint4 g1 = *(const uint4*)&base[(unsigned)__shfl(sv, 2 + half) * 256];
    uint4 g2 = *(const uint4*)&base[(unsigned)__shfl(sv, 4 + half) * 256];
    uint4 g3 = *(const uint4*)&base[(unsigned)__shfl(sv, 6 + half) * 256];
    for (int i = start; i < end; i += 8) {
        int inext = i + 8;
        int sv_n = ssrc[min(inext + e8, last)];
        int se_n = __shfl(sv_n, h);
        float av_n = as1[se_n * HEADS + e8];
        uint4 n0 = *(const uint4*)&base[(unsigned)__shfl(sv_n, 0 + half) * 256];
        uint4 n1 = *(const uint4*)&base[(unsigned)__shfl(sv_n, 2 + half) * 256];
        uint4 n2 = *(const uint4*)&base[(unsigned)__shfl(sv_n, 4 + half) * 256];
        uint4 n3 = *(const uint4*)&base[(unsigned)__shfl(sv_n, 6 + half) * 256];
        float wv = explrelu(av + ad_w);
        float w0 = __shfl(wv, (0 + half) * 8 + hh);
        float w1 = __shfl(wv, (2 + half) * 8 + hh);
        float w2 = __shfl(wv, (4 + half) * 8 + hh);
        float w3 = __shfl(wv, (6 + half) * 8 + hh);
        w0 = (i + 0 + half < end) ? w0 : 0.f;
        w1 = (i + 2 + half < end) ? w1 : 0.f;
        w2 = (i + 4 + half < end) ? w2 : 0.f;
        w3 = (i + 6 + half < end) ? w3 : 0.f;
        den += w0 + w1 + w2 + w3;
        acc[0] = fmaf(w0, bflo(g0.x), acc[0]); acc[1] = fmaf(w0, bfhi(g0.x), acc[1]);
        acc[2] = fmaf(w0, bflo(g0.y), acc[2]); acc[3] = fmaf(w0, bfhi(g0.y), acc[3]);
        acc[4] = fmaf(w0, bflo(g0.z), acc[4]); acc[5] = fmaf(w0, bfhi(g0.z), acc[5]);
        acc[6] = fmaf(w0, bflo(g0.w), acc[6]); acc[7] = fmaf(w0, bfhi(g0.w), acc[7]);
        acc[0] = fmaf(w1, bflo(g1.x), acc[0]); acc[1] = fmaf(w1, bfhi(g1.x), acc[1]);
        acc[2] = fmaf(w1, bflo(g1.y), acc[2]); acc[3] = fmaf(w1, bfhi(g1.y), acc[3]);
        acc[4] = fmaf(w1, bflo(g1.z), acc[4]); acc[5] = fmaf(w1, bfhi(g1.z), acc[5]);
        acc[6] = fmaf(w1, bflo(g1.w), acc[6]); acc[7] = fmaf(w1, bfhi(g1.w), acc[7]);
        acc[0] = fmaf(w2, bflo(g2.x), acc[0]); acc[1] = fmaf(w2, bfhi(g2.x), acc[1]);
        acc[2] = fmaf(w2, bflo(g2.y), acc[2]); acc[3] = fmaf(w2, bfhi(g2.y), acc[3]);
        acc[4] = fmaf(w2, bflo(g2.z), acc[4]); acc[5] = fmaf(w2, bfhi(g2.z), acc[5]);
        acc[6] = fmaf(w2, bflo(g2.w), acc[6]); acc[7] = fmaf(w2, bfhi(g2.w), acc[7]);
        acc[0] = fmaf(w3, bflo(g3.x), acc[0]); acc[1] = fmaf(w3, bfhi(g3.x), acc[1]);
        acc[2] = fmaf(w3, bflo(g3.y), acc[2]); acc[3] = fmaf(w3, bfhi(g3.y), acc[3]);
        acc[4] = fmaf(w3, bflo(g3.z), acc[4]); acc[5] = fmaf(w3, bfhi(g3.z), acc[5]);
        acc[6] = fmaf(w3, bflo(g3.w), acc[6]); acc[7] = fmaf(w3, bfhi(g3.w), acc[7]);
        g0 = n0; g1 = n1; g2 = n2; g3 = n3;
        sv = sv_n; av = av_n;
    }
#pragma unroll
    for (int j = 0; j < 8; ++j) acc[j] += __shfl_xor(acc[j], 32);
    den += __shfl_xor(den, 32);
    if (lane < 32) {
        float r = __builtin_amdgcn_rcpf(den);
        float4 b0 = *(const float4*)&b1[c * 8];
        float4 b4 = *(const float4*)&b1[c * 8 + 4];
        float v0 = fmaf(acc[0], r, b0.x);
        float v1 = fmaf(acc[1], r, b0.y);
        float v2 = fmaf(acc[2], r, b0.z);
        float v3 = fmaf(acc[3], r, b0.w);
        float v4 = fmaf(acc[4], r, b4.x);
        float v5 = fmaf(acc[5], r, b4.y);
        float v6 = fmaf(acc[6], r, b4.z);
        float v7 = fmaf(acc[7], r, b4.w);
        v0 = v0 > 0.f ? v0 : expm1f(v0);
        v1 = v1 > 0.f ? v1 : expm1f(v1);
        v2 = v2 > 0.f ? v2 : expm1f(v2);
        v3 = v3 > 0.f ? v3 : expm1f(v3);
        v4 = v4 > 0.f ? v4 : expm1f(v4);
        v5 = v5 > 0.f ? v5 : expm1f(v5);
        v6 = v6 > 0.f ? v6 : expm1f(v6);
        v7 = v7 > 0.f ? v7 : expm1f(v7);
        uint4 ob;
        ob.x = (unsigned)f2bf(v0) | ((unsigned)f2bf(v1) << 16);
        ob.y = (unsigned)f2bf(v2) | ((unsigned)f2bf(v3) << 16);
        ob.z = (unsigned)f2bf(v4) | ((unsigned)f2bf(v5) << 16);
        ob.w = (unsigned)f2bf(v6) | ((unsigned)f2bf(v7) << 16);
        *(uint4*)&houtb[(unsigned)n * 256 + c * 8] = ob;
    }
}

// ---------------- GEMM2 via MFMA (bf16 in, fp32 acc) + alpha epilogue -------
__global__ __launch_bounds__(256) void gemm2_mfma(
    const unsigned short* __restrict__ hinb, const unsigned short* __restrict__ W2t,
    const float* __restrict__ att_s2, const float* __restrict__ att_d2,
    unsigned short* __restrict__ h2b, float* __restrict__ as2, float* __restrict__ ad2) {
    int t = threadIdx.x;
    int lane = t & 63;
    int w = t >> 6;
    int lrow = lane & 15;
    int kg = lane >> 4;
    int row0 = blockIdx.x * 64 + w * 16;
    int gr = min(row0 + lrow, N_NODES - 1);    // clamp loads (last block partial)
    f32x4 acc0 = {0.f, 0.f, 0.f, 0.f};
    f32x4 acc1 = {0.f, 0.f, 0.f, 0.f};
    f32x4 acc2 = {0.f, 0.f, 0.f, 0.f};
    f32x4 acc3 = {0.f, 0.f, 0.f, 0.f};
#pragma unroll
    for (int ks = 0; ks < 8; ++ks) {
        int kb = ks * 32 + kg * 8;
        union { bf16x8 v; uint4 u; } A, B0, B1, B2, B3;
        A.u  = *(const uint4*)&hinb[(size_t)gr * 256 + kb];
        B0.u = *(const uint4*)&W2t[(size_t)(0 * 16 + lrow) * 256 + kb];
        B1.u = *(const uint4*)&W2t[(size_t)(1 * 16 + lrow) * 256 + kb];
        B2.u = *(const uint4*)&W2t[(size_t)(2 * 16 + lrow) * 256 + kb];
        B3.u = *(const uint4*)&W2t[(size_t)(3 * 16 + lrow) * 256 + kb];
        acc0 = __builtin_amdgcn_mfma_f32_16x16x32_bf16(A.v, B0.v, acc0, 0, 0, 0);
        acc1 = __builtin_amdgcn_mfma_f32_16x16x32_bf16(A.v, B1.v, acc1, 0, 0, 0);
        acc2 = __builtin_amdgcn_mfma_f32_16x16x32_bf16(A.v, B2.v, acc2, 0, 0, 0);
        acc3 = __builtin_amdgcn_mfma_f32_16x16x32_bf16(A.v, B3.v, acc3, 0, 0, 0);
    }
    float s0 = att_s2[ 0 + lrow], d0 = att_d2[ 0 + lrow];
    float s1 = att_s2[16 + lrow], d1 = att_d2[16 + lrow];
    float s2 = att_s2[32 + lrow], d2 = att_d2[32 + lrow];
    float s3 = att_s2[48 + lrow], d3 = att_d2[48 + lrow];
#pragma unroll
    for (int r = 0; r < 4; ++r) {
        int orow = row0 + kg * 4 + r;
        float p = acc0[r] * s0 + acc1[r] * s1 + acc2[r] * s2 + acc3[r] * s3;
        float q = acc0[r] * d0 + acc1[r] * d1 + acc2[r] * d2 + acc3[r] * d3;
        p += __shfl_xor(p, 1); q += __shfl_xor(q, 1);
        p += __shfl_xor(p, 2); q += __shfl_xor(q, 2);
        p += __shfl_xor(p, 4); q += __shfl_xor(q, 4);
        p += __shfl_xor(p, 8); q += __shfl_xor(q, 8);
        if (orow < N_NODES) {
            h2b[(size_t)orow * 64 +  0 + lrow] = f2bf(acc0[r]);
            h2b[(size_t)orow * 64 + 16 + lrow] = f2bf(acc1[r]);
            h2b[(size_t)orow * 64 + 32 + lrow] = f2bf(acc2[r]);
            h2b[(size_t)orow * 64 + 48 + lrow] = f2bf(acc3[r]);
            if (lrow == 0) { as2[orow] = p; ad2[orow] = q; }
        }
    }
}

// ---------------- Aggregate layer 2: quad-edge wide gathers -----------------
__global__ __launch_bounds__(256) void agg2_kernel(
    const int* __restrict__ off, const int* __restrict__ ssrc,
    const unsigned short* __restrict__ h2b, const float* __restrict__ as2,
    const float* __restrict__ ad2, const float* __restrict__ b2,
    float* __restrict__ out) {
    int t = threadIdx.x;
    int lane = t & 63;
    int e8 = lane & 7;
    int q = lane & 15;
    int quarter = lane >> 4;
    int n = blockIdx.x * 4 + (t >> 6);
    int start = off[n], end = off[n + 1];
    int last = end - 1;
    float adv = ad2[n];
    float acc[4];
#pragma unroll
    for (int j = 0; j < 4; ++j) acc[j] = 0.f;
    float den = 0.f;
    int sv = ssrc[min(start + e8, last)];
    float av = as2[sv];
    for (int i = start; i < end; i += 8) {
        int inext = i + 8;
        int sv_n = ssrc[min(inext + e8, last)];
        float av_n = as2[sv_n];
        float wv = explrelu(av + adv);
#pragma unroll
        for (int k = 0; k < 2; ++k) {
            int me = 4 * k + quarter;
            float wj = __shfl(wv, me);
            int   sj = __shfl(sv, me);
            wj = (i + me < end) ? wj : 0.f;
            uint2 u = *(const uint2*)&h2b[(unsigned)sj * 64 + q * 4];
            den += wj;
            acc[0] = fmaf(wj, bflo(u.x), acc[0]);
            acc[1] = fmaf(wj, bfhi(u.x), acc[1]);
            acc[2] = fmaf(wj, bflo(u.y), acc[2]);
            acc[3] = fmaf(wj, bfhi(u.y), acc[3]);
        }
        sv = sv_n; av = av_n;
    }
#pragma unroll
    for (int j = 0; j < 4; ++j) {
        acc[j] += __shfl_xor(acc[j], 16);
        acc[j] += __shfl_xor(acc[j], 32);
    }
    den += __shfl_xor(den, 16);
    den += __shfl_xor(den, 32);
    if (lane < 16) {
        float r = __builtin_amdgcn_rcpf(den);
        float4 bv = *(const float4*)&b2[q * 4];
        float4 o;
        o.x = fmaf(acc[0], r, bv.x);
        o.y = fmaf(acc[1], r, bv.y);
        o.z = fmaf(acc[2], r, bv.z);
        o.w = fmaf(acc[3], r, bv.w);
        *(float4*)&out[(unsigned)n * 64 + q * 4] = o;
    }
}

extern "C" void kernel_launch(void* const* d_in, const int* in_sizes, int n_in,
                              void* d_out, int out_size, void* d_ws, size_t ws_size,
                              hipStream_t stream) {
    const float* x    = (const float*)d_in[0];
    const int*   ei   = (const int*)d_in[1];
    const float* W1   = (const float*)d_in[2];
    const float* ats1 = (const float*)d_in[3];
    const float* atd1 = (const float*)d_in[4];
    const float* b1   = (const float*)d_in[5];
    const float* W2   = (const float*)d_in[6];
    const float* ats2 = (const float*)d_in[7];
    const float* atd2 = (const float*)d_in[8];
    const float* b2   = (const float*)d_in[9];
    float* out = (float*)d_out;

    char* ws = (char*)d_ws;
    size_t o = 0;
    auto alloc = [&](size_t bytes) { size_t r = o; o = (o + bytes + 255) & ~255UL; return r; };
    unsigned short* h1b   = (unsigned short*)(ws + alloc((size_t)N_NODES * 256 * 2));
    unsigned short* h2inb = (unsigned short*)(ws + alloc((size_t)N_NODES * 256 * 2));
    unsigned short* h2b   = (unsigned short*)(ws + alloc((size_t)N_NODES * 64 * 2));
    unsigned short* W1t   = (unsigned short*)(ws + alloc((size_t)256 * 128 * 2));
    unsigned short* W2t   = (unsigned short*)(ws + alloc((size_t)64 * 256 * 2));
    float* as1  = (float*)(ws + alloc((size_t)N_NODES * HEADS * 4));
    float* ad1  = (float*)(ws + alloc((size_t)N_NODES * HEADS * 4));
    float* as2  = (float*)(ws + alloc((size_t)N_NODES * 4));
    float* ad2  = (float*)(ws + alloc((size_t)N_NODES * 4));
    int*   cnt  = (int*)(ws + alloc((size_t)CNT_TOT * 4));
    int*   pos  = (int*)(ws + alloc((size_t)CNT_TOT * 4));
    int*   bsum = (int*)(ws + alloc(256 * 4));
    int*   off  = (int*)(ws + alloc((size_t)(N_NODES + 1) * 4));
    int*   tmp_s = (int*)(ws + alloc((size_t)E_TOT * 4));
    int*   tmp_d = (int*)(ws + alloc((size_t)E_TOT * 4));
    int*   ssrc  = (int*)(ws + alloc((size_t)E_TOT * 4));

    // atomic-free CSR build
    hist1_kernel<<<NCHUNK, 256, 0, stream>>>(ei, cnt);
    sscan1_kernel<<<SBLK, 256, 0, stream>>>(cnt, pos, bsum);
    sscan2_kernel<<<1, 256, 0, stream>>>(bsum, SBLK);
    sscan3_kernel<<<SBLK, 256, 0, stream>>>(pos, bsum);
    scat1_kernel<<<NCHUNK, 256, 0, stream>>>(ei, pos, tmp_s, tmp_d);
    l2group_kernel<<<NBUCK, 256, 0, stream>>>(pos, tmp_s, tmp_d, off, ssrc);

    // layer 1
    w1cast_kernel<<<128, 256, 0, stream>>>(W1, W1t);
    gemm1_mfma<<<G1BLK, 256, 0, stream>>>(x, W1t, ats1, atd1, h1b, as1, ad1);
    agg1_kernel<<<ABLK, 256, 0, stream>>>(off, ssrc, h1b, as1, ad1, b1, h2inb);

    // layer 2
    w2cast_kernel<<<64, 256, 0, stream>>>(W2, W2t);
    gemm2_mfma<<<G2BLK, 256, 0, stream>>>(h2inb, W2t, ats2, atd2, h2b, as2, ad2);
    agg2_kernel<<<ABLK, 256, 0, stream>>>(off, ssrc, h2b, as2, ad2, b2, out);
}

// Round 23
// 192.023 us; speedup vs baseline: 1.1580x; 1.0734x over previous
//
#include <hip/hip_runtime.h>
#include <hip/hip_bf16.h>
#include <math.h>

#define N_NODES 50000
#define N_EDGES 800000
#define E_TOT   (N_EDGES + N_NODES)   // 850000 (with self-loops)
#define IN_CH 128
#define HID 32
#define HEADS 8
#define OUT_CH 64
#define NEG_SLOPE 0.2f
#define G1BLK 3125                    // 50000/16 rows per MFMA block
#define G2BLK 782                     // ceil(50000/64)
#define ABLK 12500                    // 50000/4 nodes per 256-thread block
#define LOG2E 1.4426950408889634f

// ---- atomic-free CSR build geometry ----
#define CHUNK_E 5376                  // 21 edges/thread * 256
#define NCHUNK 159                    // ceil(850000/5376)
#define NBUCK 391                     // dst>>7, max 49999>>7 = 390
#define CNT_TOT (NBUCK * NCHUNK)      // 62169
#define SBLK 243                      // ceil(62169/256)

typedef __attribute__((ext_vector_type(8))) short bf16x8;
typedef __attribute__((ext_vector_type(4))) float f32x4;

__device__ __forceinline__ float explrelu(float z) {
    return exp2f(fmaxf(z * LOG2E, z * (NEG_SLOPE * LOG2E)));
}

__device__ __forceinline__ unsigned short f2bf(float f) {
    unsigned int u = __float_as_uint(f);
    unsigned int r = (u + 0x7FFFu + ((u >> 16) & 1u)) >> 16;   // round-nearest-even
    return (unsigned short)r;
}
__device__ __forceinline__ float bf2f(unsigned short u) {
    return __uint_as_float(((unsigned int)u) << 16);
}
__device__ __forceinline__ float bflo(unsigned int u) {
    return __uint_as_float(u << 16);
}
__device__ __forceinline__ float bfhi(unsigned int u) {
    return __uint_as_float(u & 0xFFFF0000u);
}

// ---------------- fuseA: per-chunk bucket histogram + W1 cast ---------------
__global__ __launch_bounds__(256) void fuseA_kernel(
    const int* __restrict__ ei, int* __restrict__ cnt,
    const float* __restrict__ W1, unsigned short* __restrict__ W1t) {
    __shared__ int hist[NBUCK];
    int t = threadIdx.x, b = blockIdx.x;
    if (b < NCHUNK) {
        for (int j = t; j < NBUCK; j += 256) hist[j] = 0;
        __syncthreads();
#pragma unroll
        for (int i = 0; i < 21; ++i) {
            int e = b * CHUNK_E + i * 256 + t;
            if (e < E_TOT) {
                int d = (e < N_EDGES) ? ei[N_EDGES + e] : (e - N_EDGES);
                atomicAdd(&hist[d >> 7], 1);
            }
        }
        __syncthreads();
        for (int j = t; j < NBUCK; j += 256) cnt[j * NCHUNK + b] = hist[j];
    } else {
        int i = (b - NCHUNK) * 256 + t;        // 32768 elems, 128 blocks
        int col = i >> 7, k = i & 127;
        W1t[i] = f2bf(W1[k * 256 + col]);
    }
}

// ---------------- scan of cnt (bucket-major), 3-kernel pattern --------------
__global__ void sscan1_kernel(const int* __restrict__ cnt, int* __restrict__ pos,
                              int* __restrict__ bsum) {
    __shared__ int s[256];
    int b = blockIdx.x, t = threadIdx.x, g = b * 256 + t;
    int v = (g < CNT_TOT) ? cnt[g] : 0;
    s[t] = v;
    __syncthreads();
    for (int d = 1; d < 256; d <<= 1) {
        int o = (t >= d) ? s[t - d] : 0;
        __syncthreads();
        s[t] += o;
        __syncthreads();
    }
    if (g < CNT_TOT) pos[g] = s[t] - v;
    if (t == 255) bsum[b] = s[t];
}

__global__ void sscan2_kernel(int* __restrict__ bsum, int nb) {
    __shared__ int s[256];
    int t = threadIdx.x;
    int v = (t < nb) ? bsum[t] : 0;
    s[t] = v;
    __syncthreads();
    for (int d = 1; d < 256; d <<= 1) {
        int o = (t >= d) ? s[t - d] : 0;
        __syncthreads();
        s[t] += o;
        __syncthreads();
    }
    if (t < nb) bsum[t] = s[t] - v;
}

__global__ void sscan3_kernel(int* __restrict__ pos, const int* __restrict__ bsum) {
    int b = blockIdx.x, t = threadIdx.x, g = b * 256 + t;
    if (g < CNT_TOT) pos[g] += bsum[b];
}

// ---------------- GEMM1 body (device fn) ------------------------------------
__device__ __forceinline__ void gemm1_body(
    int blk, int t,
    const float* __restrict__ x, const unsigned short* __restrict__ W1t,
    const float* __restrict__ att_s, const float* __restrict__ att_d,
    unsigned short* __restrict__ h1b, float* __restrict__ as1, float* __restrict__ ad1) {
    int lane = t & 63;
    int w = t >> 6;
    int lrow = lane & 15;
    int kg = lane >> 4;
    int row0 = blk * 16;
    int gr = row0 + lrow;                      // 3125*16 = 50000 exactly
    f32x4 acc0 = {0.f, 0.f, 0.f, 0.f};
    f32x4 acc1 = {0.f, 0.f, 0.f, 0.f};
    f32x4 acc2 = {0.f, 0.f, 0.f, 0.f};
    f32x4 acc3 = {0.f, 0.f, 0.f, 0.f};
#pragma unroll
    for (int ks = 0; ks < 4; ++ks) {
        const float* ap = &x[(size_t)gr * IN_CH + ks * 32 + kg * 8];
        float4 a0 = *(const float4*)ap;
        float4 a1 = *(const float4*)(ap + 4);
        union { bf16x8 v; unsigned int u[4]; } A;
        A.u[0] = ((unsigned)f2bf(a0.y) << 16) | f2bf(a0.x);
        A.u[1] = ((unsigned)f2bf(a0.w) << 16) | f2bf(a0.z);
        A.u[2] = ((unsigned)f2bf(a1.y) << 16) | f2bf(a1.x);
        A.u[3] = ((unsigned)f2bf(a1.w) << 16) | f2bf(a1.z);
        union { bf16x8 v; uint4 u; } B0, B1, B2, B3;
        int kb = ks * 32 + kg * 8;
        B0.u = *(const uint4*)&W1t[(size_t)(w * 64 + 0 * 16 + lrow) * IN_CH + kb];
        B1.u = *(const uint4*)&W1t[(size_t)(w * 64 + 1 * 16 + lrow) * IN_CH + kb];
        B2.u = *(const uint4*)&W1t[(size_t)(w * 64 + 2 * 16 + lrow) * IN_CH + kb];
        B3.u = *(const uint4*)&W1t[(size_t)(w * 64 + 3 * 16 + lrow) * IN_CH + kb];
        acc0 = __builtin_amdgcn_mfma_f32_16x16x32_bf16(A.v, B0.v, acc0, 0, 0, 0);
        acc1 = __builtin_amdgcn_mfma_f32_16x16x32_bf16(A.v, B1.v, acc1, 0, 0, 0);
        acc2 = __builtin_amdgcn_mfma_f32_16x16x32_bf16(A.v, B2.v, acc2, 0, 0, 0);
        acc3 = __builtin_amdgcn_mfma_f32_16x16x32_bf16(A.v, B3.v, acc3, 0, 0, 0);
    }
    float s0 = att_s[w * 64 + 0 * 16 + lrow], d0 = att_d[w * 64 + 0 * 16 + lrow];
    float s1 = att_s[w * 64 + 1 * 16 + lrow], d1 = att_d[w * 64 + 1 * 16 + lrow];
    float s2 = att_s[w * 64 + 2 * 16 + lrow], d2 = att_d[w * 64 + 2 * 16 + lrow];
    float s3 = att_s[w * 64 + 3 * 16 + lrow], d3 = att_d[w * 64 + 3 * 16 + lrow];
#pragma unroll
    for (int r = 0; r < 4; ++r) {
        int orow = row0 + kg * 4 + r;
        h1b[(size_t)orow * 256 + w * 64 +  0 + lrow] = f2bf(acc0[r]);
        h1b[(size_t)orow * 256 + w * 64 + 16 + lrow] = f2bf(acc1[r]);
        h1b[(size_t)orow * 256 + w * 64 + 32 + lrow] = f2bf(acc2[r]);
        h1b[(size_t)orow * 256 + w * 64 + 48 + lrow] = f2bf(acc3[r]);
        float p0 = acc0[r] * s0 + acc1[r] * s1;
        float q0 = acc0[r] * d0 + acc1[r] * d1;
        float p1 = acc2[r] * s2 + acc3[r] * s3;
        float q1 = acc2[r] * d2 + acc3[r] * d3;
        p0 += __shfl_xor(p0, 1); q0 += __shfl_xor(q0, 1);
        p1 += __shfl_xor(p1, 1); q1 += __shfl_xor(q1, 1);
        p0 += __shfl_xor(p0, 2); q0 += __shfl_xor(q0, 2);
        p1 += __shfl_xor(p1, 2); q1 += __shfl_xor(q1, 2);
        p0 += __shfl_xor(p0, 4); q0 += __shfl_xor(q0, 4);
        p1 += __shfl_xor(p1, 4); q1 += __shfl_xor(q1, 4);
        p0 += __shfl_xor(p0, 8); q0 += __shfl_xor(q0, 8);
        p1 += __shfl_xor(p1, 8); q1 += __shfl_xor(q1, 8);
        if (lrow == 0) {
            as1[orow * HEADS + 2 * w]     = p0;
            ad1[orow * HEADS + 2 * w]     = q0;
            as1[orow * HEADS + 2 * w + 1] = p1;
            ad1[orow * HEADS + 2 * w + 1] = q1;
        }
    }
}

// ---------------- fuseB: bucket scatter + GEMM1 (MFMA) ----------------------
__global__ __launch_bounds__(256) void fuseB_kernel(
    const int* __restrict__ ei, const int* __restrict__ pos,
    int* __restrict__ tmp_s, int* __restrict__ tmp_d,
    const float* __restrict__ x, const unsigned short* __restrict__ W1t,
    const float* __restrict__ att_s, const float* __restrict__ att_d,
    unsigned short* __restrict__ h1b, float* __restrict__ as1, float* __restrict__ ad1) {
    int t = threadIdx.x, b = blockIdx.x;
    if (b < NCHUNK) {
        __shared__ int cur[NBUCK];
        for (int j = t; j < NBUCK; j += 256) cur[j] = pos[j * NCHUNK + b];
        __syncthreads();
#pragma unroll
        for (int i = 0; i < 21; ++i) {
            int e = b * CHUNK_E + i * 256 + t;
            if (e < E_TOT) {
                int s, d;
                if (e < N_EDGES) { s = ei[e]; d = ei[N_EDGES + e]; }
                else             { s = d = e - N_EDGES; }
                int p = atomicAdd(&cur[d >> 7], 1);   // LDS atomic
                tmp_s[p] = s;
                tmp_d[p] = d;
            }
        }
    } else {
        gemm1_body(b - NCHUNK, t, x, W1t, att_s, att_d, h1b, as1, ad1);
    }
}

// ---------------- fuseC: per-bucket node grouping + off[] + W2 cast ---------
__global__ __launch_bounds__(256) void fuseC_kernel(
    const int* __restrict__ pos, const int* __restrict__ tmp_s,
    const int* __restrict__ tmp_d, int* __restrict__ off, int* __restrict__ ssrc,
    const float* __restrict__ W2, unsigned short* __restrict__ W2t) {
    int b = blockIdx.x, t = threadIdx.x;
    if (b < NBUCK) {
        __shared__ int nc[128];
        __shared__ int sc[128];
        int seg_start = pos[b * NCHUNK];
        int seg_end = (b + 1 < NBUCK) ? pos[(b + 1) * NCHUNK] : E_TOT;
        if (t < 128) nc[t] = 0;
        __syncthreads();
        for (int i = seg_start + t; i < seg_end; i += 256)
            atomicAdd(&nc[tmp_d[i] & 127], 1);
        __syncthreads();
        if (t < 128) sc[t] = nc[t];
        __syncthreads();
        for (int dd = 1; dd < 128; dd <<= 1) {
            int v = 0;
            if (t < 128 && t >= dd) v = sc[t - dd];
            __syncthreads();
            if (t < 128) sc[t] += v;
            __syncthreads();
        }
        if (t < 128) {
            int excl = sc[t] - nc[t];
            int node = b * 128 + t;
            if (node < N_NODES) off[node] = seg_start + excl;
            nc[t] = seg_start + excl;                 // reuse as cursor
        }
        if (b == 0 && t == 0) off[N_NODES] = E_TOT;
        __syncthreads();
        for (int i = seg_start + t; i < seg_end; i += 256) {
            int d = tmp_d[i];
            int p = atomicAdd(&nc[d & 127], 1);       // LDS atomic
            ssrc[p] = tmp_s[i];
        }
    } else {
        int i = (b - NBUCK) * 256 + t;                // 16384 elems, 64 blocks
        int col = i >> 8, k = i & 255;
        W2t[i] = f2bf(W2[k * 64 + col]);
    }
}

// ---------------- Aggregate layer 1: dual-edge wide gathers, 2-deep pipe ----
__global__ __launch_bounds__(256) void agg1_kernel(
    const int* __restrict__ off, const int* __restrict__ ssrc,
    const unsigned short* __restrict__ h1b, const float* __restrict__ as1,
    const float* __restrict__ ad1, const float* __restrict__ b1,
    unsigned short* __restrict__ houtb) {
    int t = threadIdx.x;
    int lane = t & 63;
    int n = blockIdx.x * 4 + (t >> 6);
    int h    = lane >> 3;     // weight-phase head
    int e8   = lane & 7;      // weight-phase edge slot
    int c    = lane & 31;     // channel group: ushorts [c*8, c*8+8)
    int hh   = c >> 2;        // head of my channel group
    int half = lane >> 5;     // 0: even edges, 1: odd edges
    int start = off[n], end = off[n + 1];
    int last = end - 1;
    float ad_w = ad1[n * HEADS + e8];
    float acc[8];
#pragma unroll
    for (int j = 0; j < 8; ++j) acc[j] = 0.f;
    float den = 0.f;
    int sv = ssrc[min(start + e8, last)];
    int se = __shfl(sv, h);
    float av = as1[se * HEADS + e8];
    const unsigned short* base = h1b + c * 8;
    uint4 g0 = *(const uint4*)&base[(unsigned)__shfl(sv, 0 + half) * 256];
    uint4 g1 = *(const uint4*)&base[(unsigned)__shfl(sv, 2 + half) * 256];
    uint4 g2 = *(const uint4*)&base[(unsigned)__shfl(sv, 4 + half) * 256];
    uint4 g3 = *(const uint4*)&base[(unsigned)__shfl(sv, 6 + half) * 256];
    for (int i = start; i < end; i += 8) {
        int inext = i + 8;
        int sv_n = ssrc[min(inext + e8, last)];
        int se_n = __shfl(sv_n, h);
        float av_n = as1[se_n * HEADS + e8];
        uint4 n0 = *(const uint4*)&base[(unsigned)__shfl(sv_n, 0 + half) * 256];
        uint4 n1 = *(const uint4*)&base[(unsigned)__shfl(sv_n, 2 + half) * 256];
        uint4 n2 = *(const uint4*)&base[(unsigned)__shfl(sv_n, 4 + half) * 256];
        uint4 n3 = *(const uint4*)&base[(unsigned)__shfl(sv_n, 6 + half) * 256];
        float wv = explrelu(av + ad_w);
        float w0 = __shfl(wv, (0 + half) * 8 + hh);
        float w1 = __shfl(wv, (2 + half) * 8 + hh);
        float w2 = __shfl(wv, (4 + half) * 8 + hh);
        float w3 = __shfl(wv, (6 + half) * 8 + hh);
        w0 = (i + 0 + half < end) ? w0 : 0.f;
        w1 = (i + 2 + half < end) ? w1 : 0.f;
        w2 = (i + 4 + half < end) ? w2 : 0.f;
        w3 = (i + 6 + half < end) ? w3 : 0.f;
        den += w0 + w1 + w2 + w3;
        acc[0] = fmaf(w0, bflo(g0.x), acc[0]); acc[1] = fmaf(w0, bfhi(g0.x), acc[1]);
        acc[2] = fmaf(w0, bflo(g0.y), acc[2]); acc[3] = fmaf(w0, bfhi(g0.y), acc[3]);
        acc[4] = fmaf(w0, bflo(g0.z), acc[4]); acc[5] = fmaf(w0, bfhi(g0.z), acc[5]);
        acc[6] = fmaf(w0, bflo(g0.w), acc[6]); acc[7] = fmaf(w0, bfhi(g0.w), acc[7]);
        acc[0] = fmaf(w1, bflo(g1.x), acc[0]); acc[1] = fmaf(w1, bfhi(g1.x), acc[1]);
        acc[2] = fmaf(w1, bflo(g1.y), acc[2]); acc[3] = fmaf(w1, bfhi(g1.y), acc[3]);
        acc[4] = fmaf(w1, bflo(g1.z), acc[4]); acc[5] = fmaf(w1, bfhi(g1.z), acc[5]);
        acc[6] = fmaf(w1, bflo(g1.w), acc[6]); acc[7] = fmaf(w1, bfhi(g1.w), acc[7]);
        acc[0] = fmaf(w2, bflo(g2.x), acc[0]); acc[1] = fmaf(w2, bfhi(g2.x), acc[1]);
        acc[2] = fmaf(w2, bflo(g2.y), acc[2]); acc[3] = fmaf(w2, bfhi(g2.y), acc[3]);
        acc[4] = fmaf(w2, bflo(g2.z), acc[4]); acc[5] = fmaf(w2, bfhi(g2.z), acc[5]);
        acc[6] = fmaf(w2, bflo(g2.w), acc[6]); acc[7] = fmaf(w2, bfhi(g2.w), acc[7]);
        acc[0] = fmaf(w3, bflo(g3.x), acc[0]); acc[1] = fmaf(w3, bfhi(g3.x), acc[1]);
        acc[2] = fmaf(w3, bflo(g3.y), acc[2]); acc[3] = fmaf(w3, bfhi(g3.y), acc[3]);
        acc[4] = fmaf(w3, bflo(g3.z), acc[4]); acc[5] = fmaf(w3, bfhi(g3.z), acc[5]);
        acc[6] = fmaf(w3, bflo(g3.w), acc[6]); acc[7] = fmaf(w3, bfhi(g3.w), acc[7]);
        g0 = n0; g1 = n1; g2 = n2; g3 = n3;
        sv = sv_n; av = av_n;
    }
#pragma unroll
    for (int j = 0; j < 8; ++j) acc[j] += __shfl_xor(acc[j], 32);
    den += __shfl_xor(den, 32);
    if (lane < 32) {
        float r = __builtin_amdgcn_rcpf(den);
        float4 b0 = *(const float4*)&b1[c * 8];
        float4 b4 = *(const float4*)&b1[c * 8 + 4];
        float v0 = fmaf(acc[0], r, b0.x);
        float v1 = fmaf(acc[1], r, b0.y);
        float v2 = fmaf(acc[2], r, b0.z);
        float v3 = fmaf(acc[3], r, b0.w);
        float v4 = fmaf(acc[4], r, b4.x);
        float v5 = fmaf(acc[5], r, b4.y);
        float v6 = fmaf(acc[6], r, b4.z);
        float v7 = fmaf(acc[7], r, b4.w);
        v0 = v0 > 0.f ? v0 : expm1f(v0);
        v1 = v1 > 0.f ? v1 : expm1f(v1);
        v2 = v2 > 0.f ? v2 : expm1f(v2);
        v3 = v3 > 0.f ? v3 : expm1f(v3);
        v4 = v4 > 0.f ? v4 : expm1f(v4);
        v5 = v5 > 0.f ? v5 : expm1f(v5);
        v6 = v6 > 0.f ? v6 : expm1f(v6);
        v7 = v7 > 0.f ? v7 : expm1f(v7);
        uint4 ob;
        ob.x = (unsigned)f2bf(v0) | ((unsigned)f2bf(v1) << 16);
        ob.y = (unsigned)f2bf(v2) | ((unsigned)f2bf(v3) << 16);
        ob.z = (unsigned)f2bf(v4) | ((unsigned)f2bf(v5) << 16);
        ob.w = (unsigned)f2bf(v6) | ((unsigned)f2bf(v7) << 16);
        *(uint4*)&houtb[(unsigned)n * 256 + c * 8] = ob;
    }
}

// ---------------- GEMM2 via MFMA (bf16 in, fp32 acc) + alpha epilogue -------
__global__ __launch_bounds__(256) void gemm2_mfma(
    const unsigned short* __restrict__ hinb, const unsigned short* __restrict__ W2t,
    const float* __restrict__ att_s2, const float* __restrict__ att_d2,
    unsigned short* __restrict__ h2b, float* __restrict__ as2, float* __restrict__ ad2) {
    int t = threadIdx.x;
    int lane = t & 63;
    int w = t >> 6;
    int lrow = lane & 15;
    int kg = lane >> 4;
    int row0 = blockIdx.x * 64 + w * 16;
    int gr = min(row0 + lrow, N_NODES - 1);    // clamp loads (last block partial)
    f32x4 acc0 = {0.f, 0.f, 0.f, 0.f};
    f32x4 acc1 = {0.f, 0.f, 0.f, 0.f};
    f32x4 acc2 = {0.f, 0.f, 0.f, 0.f};
    f32x4 acc3 = {0.f, 0.f, 0.f, 0.f};
#pragma unroll
    for (int ks = 0; ks < 8; ++ks) {
        int kb = ks * 32 + kg * 8;
        union { bf16x8 v; uint4 u; } A, B0, B1, B2, B3;
        A.u  = *(const uint4*)&hinb[(size_t)gr * 256 + kb];
        B0.u = *(const uint4*)&W2t[(size_t)(0 * 16 + lrow) * 256 + kb];
        B1.u = *(const uint4*)&W2t[(size_t)(1 * 16 + lrow) * 256 + kb];
        B2.u = *(const uint4*)&W2t[(size_t)(2 * 16 + lrow) * 256 + kb];
        B3.u = *(const uint4*)&W2t[(size_t)(3 * 16 + lrow) * 256 + kb];
        acc0 = __builtin_amdgcn_mfma_f32_16x16x32_bf16(A.v, B0.v, acc0, 0, 0, 0);
        acc1 = __builtin_amdgcn_mfma_f32_16x16x32_bf16(A.v, B1.v, acc1, 0, 0, 0);
        acc2 = __builtin_amdgcn_mfma_f32_16x16x32_bf16(A.v, B2.v, acc2, 0, 0, 0);
        acc3 = __builtin_amdgcn_mfma_f32_16x16x32_bf16(A.v, B3.v, acc3, 0, 0, 0);
    }
    float s0 = att_s2[ 0 + lrow], d0 = att_d2[ 0 + lrow];
    float s1 = att_s2[16 + lrow], d1 = att_d2[16 + lrow];
    float s2 = att_s2[32 + lrow], d2 = att_d2[32 + lrow];
    float s3 = att_s2[48 + lrow], d3 = att_d2[48 + lrow];
#pragma unroll
    for (int r = 0; r < 4; ++r) {
        int orow = row0 + kg * 4 + r;
        float p = acc0[r] * s0 + acc1[r] * s1 + acc2[r] * s2 + acc3[r] * s3;
        float q = acc0[r] * d0 + acc1[r] * d1 + acc2[r] * d2 + acc3[r] * d3;
        p += __shfl_xor(p, 1); q += __shfl_xor(q, 1);
        p += __shfl_xor(p, 2); q += __shfl_xor(q, 2);
        p += __shfl_xor(p, 4); q += __shfl_xor(q, 4);
        p += __shfl_xor(p, 8); q += __shfl_xor(q, 8);
        if (orow < N_NODES) {
            h2b[(size_t)orow * 64 +  0 + lrow] = f2bf(acc0[r]);
            h2b[(size_t)orow * 64 + 16 + lrow] = f2bf(acc1[r]);
            h2b[(size_t)orow * 64 + 32 + lrow] = f2bf(acc2[r]);
            h2b[(size_t)orow * 64 + 48 + lrow] = f2bf(acc3[r]);
            if (lrow == 0) { as2[orow] = p; ad2[orow] = q; }
        }
    }
}

// ---------------- Aggregate layer 2: quad-edge wide gathers -----------------
__global__ __launch_bounds__(256) void agg2_kernel(
    const int* __restrict__ off, const int* __restrict__ ssrc,
    const unsigned short* __restrict__ h2b, const float* __restrict__ as2,
    const float* __restrict__ ad2, const float* __restrict__ b2,
    float* __restrict__ out) {
    int t = threadIdx.x;
    int lane = t & 63;
    int e8 = lane & 7;
    int q = lane & 15;
    int quarter = lane >> 4;
    int n = blockIdx.x * 4 + (t >> 6);
    int start = off[n], end = off[n + 1];
    int last = end - 1;
    float adv = ad2[n];
    float acc[4];
#pragma unroll
    for (int j = 0; j < 4; ++j) acc[j] = 0.f;
    float den = 0.f;
    int sv = ssrc[min(start + e8, last)];
    float av = as2[sv];
    for (int i = start; i < end; i += 8) {
        int inext = i + 8;
        int sv_n = ssrc[min(inext + e8, last)];
        float av_n = as2[sv_n];
        float wv = explrelu(av + adv);
#pragma unroll
        for (int k = 0; k < 2; ++k) {
            int me = 4 * k + quarter;
            float wj = __shfl(wv, me);
            int   sj = __shfl(sv, me);
            wj = (i + me < end) ? wj : 0.f;
            uint2 u = *(const uint2*)&h2b[(unsigned)sj * 64 + q * 4];
            den += wj;
            acc[0] = fmaf(wj, bflo(u.x), acc[0]);
            acc[1] = fmaf(wj, bfhi(u.x), acc[1]);
            acc[2] = fmaf(wj, bflo(u.y), acc[2]);
            acc[3] = fmaf(wj, bfhi(u.y), acc[3]);
        }
        sv = sv_n; av = av_n;
    }
#pragma unroll
    for (int j = 0; j < 4; ++j) {
        acc[j] += __shfl_xor(acc[j], 16);
        acc[j] += __shfl_xor(acc[j], 32);
    }
    den += __shfl_xor(den, 16);
    den += __shfl_xor(den, 32);
    if (lane < 16) {
        float r = __builtin_amdgcn_rcpf(den);
        float4 bv = *(const float4*)&b2[q * 4];
        float4 o;
        o.x = fmaf(acc[0], r, bv.x);
        o.y = fmaf(acc[1], r, bv.y);
        o.z = fmaf(acc[2], r, bv.z);
        o.w = fmaf(acc[3], r, bv.w);
        *(float4*)&out[(unsigned)n * 64 + q * 4] = o;
    }
}

extern "C" void kernel_launch(void* const* d_in, const int* in_sizes, int n_in,
                              void* d_out, int out_size, void* d_ws, size_t ws_size,
                              hipStream_t stream) {
    const float* x    = (const float*)d_in[0];
    const int*   ei   = (const int*)d_in[1];
    const float* W1   = (const float*)d_in[2];
    const float* ats1 = (const float*)d_in[3];
    const float* atd1 = (const float*)d_in[4];
    const float* b1   = (const float*)d_in[5];
    const float* W2   = (const float*)d_in[6];
    const float* ats2 = (const float*)d_in[7];
    const float* atd2 = (const float*)d_in[8];
    const float* b2   = (const float*)d_in[9];
    float* out = (float*)d_out;

    char* ws = (char*)d_ws;
    size_t o = 0;
    auto alloc = [&](size_t bytes) { size_t r = o; o = (o + bytes + 255) & ~255UL; return r; };
    unsigned short* h1b   = (unsigned short*)(ws + alloc((size_t)N_NODES * 256 * 2));
    unsigned short* h2inb = (unsigned short*)(ws + alloc((size_t)N_NODES * 256 * 2));
    unsigned short* h2b   = (unsigned short*)(ws + alloc((size_t)N_NODES * 64 * 2));
    unsigned short* W1t   = (unsigned short*)(ws + alloc((size_t)256 * 128 * 2));
    unsigned short* W2t   = (unsigned short*)(ws + alloc((size_t)64 * 256 * 2));
    float* as1  = (float*)(ws + alloc((size_t)N_NODES * HEADS * 4));
    float* ad1  = (float*)(ws + alloc((size_t)N_NODES * HEADS * 4));
    float* as2  = (float*)(ws + alloc((size_t)N_NODES * 4));
    float* ad2  = (float*)(ws + alloc((size_t)N_NODES * 4));
    int*   cnt  = (int*)(ws + alloc((size_t)CNT_TOT * 4));
    int*   pos  = (int*)(ws + alloc((size_t)CNT_TOT * 4));
    int*   bsum = (int*)(ws + alloc(256 * 4));
    int*   off  = (int*)(ws + alloc((size_t)(N_NODES + 1) * 4));
    int*   tmp_s = (int*)(ws + alloc((size_t)E_TOT * 4));
    int*   tmp_d = (int*)(ws + alloc((size_t)E_TOT * 4));
    int*   ssrc  = (int*)(ws + alloc((size_t)E_TOT * 4));

    // CSR build (atomic-free) with fused independent work
    fuseA_kernel<<<NCHUNK + 128, 256, 0, stream>>>(ei, cnt, W1, W1t);
    sscan1_kernel<<<SBLK, 256, 0, stream>>>(cnt, pos, bsum);
    sscan2_kernel<<<1, 256, 0, stream>>>(bsum, SBLK);
    sscan3_kernel<<<SBLK, 256, 0, stream>>>(pos, bsum);
    fuseB_kernel<<<NCHUNK + G1BLK, 256, 0, stream>>>(
        ei, pos, tmp_s, tmp_d, x, W1t, ats1, atd1, h1b, as1, ad1);
    fuseC_kernel<<<NBUCK + 64, 256, 0, stream>>>(pos, tmp_s, tmp_d, off, ssrc, W2, W2t);

    // layer 1 aggregate
    agg1_kernel<<<ABLK, 256, 0, stream>>>(off, ssrc, h1b, as1, ad1, b1, h2inb);

    // layer 2
    gemm2_mfma<<<G2BLK, 256, 0, stream>>>(h2inb, W2t, ats2, atd2, h2b, as2, ad2);
    agg2_kernel<<<ABLK, 256, 0, stream>>>(off, ssrc, h2b, as2, ad2, b2, out);
}

// Round 24
// 184.825 us; speedup vs baseline: 1.2031x; 1.0389x over previous
//
#include <hip/hip_runtime.h>
#include <hip/hip_bf16.h>
#include <math.h>

#define N_NODES 50000
#define N_EDGES 800000
#define E_TOT   (N_EDGES + N_NODES)   // 850000 (with self-loops)
#define IN_CH 128
#define HID 32
#define HEADS 8
#define OUT_CH 64
#define NEG_SLOPE 0.2f
#define G1BLK 3125                    // 50000/16 rows per MFMA block
#define G2BLK 782                     // ceil(50000/64)
#define ABLK 12500                    // 50000/4 nodes per 256-thread block
#define LOG2E 1.4426950408889634f

// ---- atomic-free CSR build geometry ----
#define CHUNK_E 5376                  // 21 edges/thread * 256
#define NCHUNK 159                    // ceil(850000/5376)
#define NBUCK 391                     // dst>>7, max 49999>>7 = 390
#define CNT_TOT (NBUCK * NCHUNK)      // 62169
#define SBLK 243                      // ceil(62169/256)

typedef __attribute__((ext_vector_type(8))) short bf16x8;
typedef __attribute__((ext_vector_type(4))) float f32x4;

__device__ __forceinline__ float explrelu(float z) {
    return exp2f(fmaxf(z * LOG2E, z * (NEG_SLOPE * LOG2E)));
}

__device__ __forceinline__ unsigned short f2bf(float f) {
    unsigned int u = __float_as_uint(f);
    unsigned int r = (u + 0x7FFFu + ((u >> 16) & 1u)) >> 16;   // round-nearest-even
    return (unsigned short)r;
}
__device__ __forceinline__ float bf2f(unsigned short u) {
    return __uint_as_float(((unsigned int)u) << 16);
}
__device__ __forceinline__ float bflo(unsigned int u) {
    return __uint_as_float(u << 16);
}
__device__ __forceinline__ float bfhi(unsigned int u) {
    return __uint_as_float(u & 0xFFFF0000u);
}

// ---------------- fuseA: per-chunk bucket histogram + W1 cast ---------------
__global__ __launch_bounds__(256) void fuseA_kernel(
    const int* __restrict__ ei, int* __restrict__ cnt,
    const float* __restrict__ W1, unsigned short* __restrict__ W1t) {
    __shared__ int hist[NBUCK];
    int t = threadIdx.x, b = blockIdx.x;
    if (b < NCHUNK) {
        for (int j = t; j < NBUCK; j += 256) hist[j] = 0;
        __syncthreads();
#pragma unroll
        for (int i = 0; i < 21; ++i) {
            int e = b * CHUNK_E + i * 256 + t;
            if (e < E_TOT) {
                int d = (e < N_EDGES) ? ei[N_EDGES + e] : (e - N_EDGES);
                atomicAdd(&hist[d >> 7], 1);
            }
        }
        __syncthreads();
        for (int j = t; j < NBUCK; j += 256) cnt[j * NCHUNK + b] = hist[j];
    } else {
        int i = (b - NCHUNK) * 256 + t;        // 32768 elems, 128 blocks
        int col = i >> 7, k = i & 127;
        W1t[i] = f2bf(W1[k * 256 + col]);
    }
}

// ---------------- scan of cnt: partial (sscan1) + block offsets (sscan2) ----
__global__ void sscan1_kernel(const int* __restrict__ cnt, int* __restrict__ pos,
                              int* __restrict__ bsum) {
    __shared__ int s[256];
    int b = blockIdx.x, t = threadIdx.x, g = b * 256 + t;
    int v = (g < CNT_TOT) ? cnt[g] : 0;
    s[t] = v;
    __syncthreads();
    for (int d = 1; d < 256; d <<= 1) {
        int o = (t >= d) ? s[t - d] : 0;
        __syncthreads();
        s[t] += o;
        __syncthreads();
    }
    if (g < CNT_TOT) pos[g] = s[t] - v;        // within-block exclusive prefix
    if (t == 255) bsum[b] = s[t];
}

__global__ void sscan2_kernel(int* __restrict__ bsum, int nb) {
    __shared__ int s[256];
    int t = threadIdx.x;
    int v = (t < nb) ? bsum[t] : 0;
    s[t] = v;
    __syncthreads();
    for (int d = 1; d < 256; d <<= 1) {
        int o = (t >= d) ? s[t - d] : 0;
        __syncthreads();
        s[t] += o;
        __syncthreads();
    }
    if (t < nb) bsum[t] = s[t] - v;            // exclusive block offsets
}

// ---------------- GEMM1 body (device fn) ------------------------------------
__device__ __forceinline__ void gemm1_body(
    int blk, int t,
    const float* __restrict__ x, const unsigned short* __restrict__ W1t,
    const float* __restrict__ att_s, const float* __restrict__ att_d,
    unsigned short* __restrict__ h1b, float* __restrict__ as1, float* __restrict__ ad1) {
    int lane = t & 63;
    int w = t >> 6;
    int lrow = lane & 15;
    int kg = lane >> 4;
    int row0 = blk * 16;
    int gr = row0 + lrow;                      // 3125*16 = 50000 exactly
    f32x4 acc0 = {0.f, 0.f, 0.f, 0.f};
    f32x4 acc1 = {0.f, 0.f, 0.f, 0.f};
    f32x4 acc2 = {0.f, 0.f, 0.f, 0.f};
    f32x4 acc3 = {0.f, 0.f, 0.f, 0.f};
#pragma unroll
    for (int ks = 0; ks < 4; ++ks) {
        const float* ap = &x[(size_t)gr * IN_CH + ks * 32 + kg * 8];
        float4 a0 = *(const float4*)ap;
        float4 a1 = *(const float4*)(ap + 4);
        union { bf16x8 v; unsigned int u[4]; } A;
        A.u[0] = ((unsigned)f2bf(a0.y) << 16) | f2bf(a0.x);
        A.u[1] = ((unsigned)f2bf(a0.w) << 16) | f2bf(a0.z);
        A.u[2] = ((unsigned)f2bf(a1.y) << 16) | f2bf(a1.x);
        A.u[3] = ((unsigned)f2bf(a1.w) << 16) | f2bf(a1.z);
        union { bf16x8 v; uint4 u; } B0, B1, B2, B3;
        int kb = ks * 32 + kg * 8;
        B0.u = *(const uint4*)&W1t[(size_t)(w * 64 + 0 * 16 + lrow) * IN_CH + kb];
        B1.u = *(const uint4*)&W1t[(size_t)(w * 64 + 1 * 16 + lrow) * IN_CH + kb];
        B2.u = *(const uint4*)&W1t[(size_t)(w * 64 + 2 * 16 + lrow) * IN_CH + kb];
        B3.u = *(const uint4*)&W1t[(size_t)(w * 64 + 3 * 16 + lrow) * IN_CH + kb];
        acc0 = __builtin_amdgcn_mfma_f32_16x16x32_bf16(A.v, B0.v, acc0, 0, 0, 0);
        acc1 = __builtin_amdgcn_mfma_f32_16x16x32_bf16(A.v, B1.v, acc1, 0, 0, 0);
        acc2 = __builtin_amdgcn_mfma_f32_16x16x32_bf16(A.v, B2.v, acc2, 0, 0, 0);
        acc3 = __builtin_amdgcn_mfma_f32_16x16x32_bf16(A.v, B3.v, acc3, 0, 0, 0);
    }
    float s0 = att_s[w * 64 + 0 * 16 + lrow], d0 = att_d[w * 64 + 0 * 16 + lrow];
    float s1 = att_s[w * 64 + 1 * 16 + lrow], d1 = att_d[w * 64 + 1 * 16 + lrow];
    float s2 = att_s[w * 64 + 2 * 16 + lrow], d2 = att_d[w * 64 + 2 * 16 + lrow];
    float s3 = att_s[w * 64 + 3 * 16 + lrow], d3 = att_d[w * 64 + 3 * 16 + lrow];
#pragma unroll
    for (int r = 0; r < 4; ++r) {
        int orow = row0 + kg * 4 + r;
        h1b[(size_t)orow * 256 + w * 64 +  0 + lrow] = f2bf(acc0[r]);
        h1b[(size_t)orow * 256 + w * 64 + 16 + lrow] = f2bf(acc1[r]);
        h1b[(size_t)orow * 256 + w * 64 + 32 + lrow] = f2bf(acc2[r]);
        h1b[(size_t)orow * 256 + w * 64 + 48 + lrow] = f2bf(acc3[r]);
        float p0 = acc0[r] * s0 + acc1[r] * s1;
        float q0 = acc0[r] * d0 + acc1[r] * d1;
        float p1 = acc2[r] * s2 + acc3[r] * s3;
        float q1 = acc2[r] * d2 + acc3[r] * d3;
        p0 += __shfl_xor(p0, 1); q0 += __shfl_xor(q0, 1);
        p1 += __shfl_xor(p1, 1); q1 += __shfl_xor(q1, 1);
        p0 += __shfl_xor(p0, 2); q0 += __shfl_xor(q0, 2);
        p1 += __shfl_xor(p1, 2); q1 += __shfl_xor(q1, 2);
        p0 += __shfl_xor(p0, 4); q0 += __shfl_xor(q0, 4);
        p1 += __shfl_xor(p1, 4); q1 += __shfl_xor(q1, 4);
        p0 += __shfl_xor(p0, 8); q0 += __shfl_xor(q0, 8);
        p1 += __shfl_xor(p1, 8); q1 += __shfl_xor(q1, 8);
        if (lrow == 0) {
            as1[orow * HEADS + 2 * w]     = p0;
            ad1[orow * HEADS + 2 * w]     = q0;
            as1[orow * HEADS + 2 * w + 1] = p1;
            ad1[orow * HEADS + 2 * w + 1] = q1;
        }
    }
}

// ---------------- fuseB: bucket scatter (packed, bsum folded) + GEMM1 -------
__global__ __launch_bounds__(256) void fuseB_kernel(
    const int* __restrict__ ei, const int* __restrict__ pos,
    const int* __restrict__ bsum, unsigned int* __restrict__ tmp,
    const float* __restrict__ x, const unsigned short* __restrict__ W1t,
    const float* __restrict__ att_s, const float* __restrict__ att_d,
    unsigned short* __restrict__ h1b, float* __restrict__ as1, float* __restrict__ ad1) {
    int t = threadIdx.x, b = blockIdx.x;
    if (b < NCHUNK) {
        __shared__ int cur[NBUCK];
        for (int j = t; j < NBUCK; j += 256) {
            int g = j * NCHUNK + b;
            cur[j] = pos[g] + bsum[g >> 8];    // fold sscan3 add here
        }
        __syncthreads();
#pragma unroll
        for (int i = 0; i < 21; ++i) {
            int e = b * CHUNK_E + i * 256 + t;
            if (e < E_TOT) {
                int s, d;
                if (e < N_EDGES) { s = ei[e]; d = ei[N_EDGES + e]; }
                else             { s = d = e - N_EDGES; }
                int p = atomicAdd(&cur[d >> 7], 1);   // LDS atomic
                tmp[p] = ((unsigned)d << 16) | (unsigned)s;   // packed (d,s)
            }
        }
    } else {
        gemm1_body(b - NCHUNK, t, x, W1t, att_s, att_d, h1b, as1, ad1);
    }
}

// ---------------- fuseC: per-bucket node grouping + off[] + W2 cast ---------
__global__ __launch_bounds__(256) void fuseC_kernel(
    const int* __restrict__ pos, const int* __restrict__ bsum,
    const unsigned int* __restrict__ tmp, int* __restrict__ off,
    int* __restrict__ ssrc,
    const float* __restrict__ W2, unsigned short* __restrict__ W2t) {
    int b = blockIdx.x, t = threadIdx.x;
    if (b < NBUCK) {
        __shared__ int nc[128];
        __shared__ int sc[128];
        int g0i = b * NCHUNK;
        int seg_start = pos[g0i] + bsum[g0i >> 8];
        int seg_end;
        if (b + 1 < NBUCK) {
            int g1i = (b + 1) * NCHUNK;
            seg_end = pos[g1i] + bsum[g1i >> 8];
        } else {
            seg_end = E_TOT;
        }
        if (t < 128) nc[t] = 0;
        __syncthreads();
        for (int i = seg_start + t; i < seg_end; i += 256)
            atomicAdd(&nc[(tmp[i] >> 16) & 127], 1);
        __syncthreads();
        if (t < 128) sc[t] = nc[t];
        __syncthreads();
        for (int dd = 1; dd < 128; dd <<= 1) {
            int v = 0;
            if (t < 128 && t >= dd) v = sc[t - dd];
            __syncthreads();
            if (t < 128) sc[t] += v;
            __syncthreads();
        }
        if (t < 128) {
            int excl = sc[t] - nc[t];
            int node = b * 128 + t;
            if (node < N_NODES) off[node] = seg_start + excl;
            nc[t] = seg_start + excl;                 // reuse as cursor
        }
        if (b == 0 && t == 0) off[N_NODES] = E_TOT;
        __syncthreads();
        for (int i = seg_start + t; i < seg_end; i += 256) {
            unsigned wrd = tmp[i];
            int p = atomicAdd(&nc[(wrd >> 16) & 127], 1);   // LDS atomic
            ssrc[p] = (int)(wrd & 0xFFFFu);
        }
    } else {
        int i = (b - NBUCK) * 256 + t;                // 16384 elems, 64 blocks
        int col = i >> 8, k = i & 255;
        W2t[i] = f2bf(W2[k * 64 + col]);
    }
}

// ---------------- Aggregate layer 1: dual-edge wide gathers, 2-deep pipe ----
__global__ __launch_bounds__(256) void agg1_kernel(
    const int* __restrict__ off, const int* __restrict__ ssrc,
    const unsigned short* __restrict__ h1b, const float* __restrict__ as1,
    const float* __restrict__ ad1, const float* __restrict__ b1,
    unsigned short* __restrict__ houtb) {
    int t = threadIdx.x;
    int lane = t & 63;
    int n = blockIdx.x * 4 + (t >> 6);
    int h    = lane >> 3;     // weight-phase head
    int e8   = lane & 7;      // weight-phase edge slot
    int c    = lane & 31;     // channel group: ushorts [c*8, c*8+8)
    int hh   = c >> 2;        // head of my channel group
    int half = lane >> 5;     // 0: even edges, 1: odd edges
    int start = off[n], end = off[n + 1];
    int last = end - 1;
    float ad_w = ad1[n * HEADS + e8];
    float acc[8];
#pragma unroll
    for (int j = 0; j < 8; ++j) acc[j] = 0.f;
    float den = 0.f;
    int sv = ssrc[min(start + e8, last)];
    int se = __shfl(sv, h);
    float av = as1[se * HEADS + e8];
    const unsigned short* base = h1b + c * 8;
    uint4 g0 = *(const uint4*)&base[(unsigned)__shfl(sv, 0 + half) * 256];
    uint4 g1 = *(const uint4*)&base[(unsigned)__shfl(sv, 2 + half) * 256];
    uint4 g2 = *(const uint4*)&base[(unsigned)__shfl(sv, 4 + half) * 256];
    uint4 g3 = *(const uint4*)&base[(unsigned)__shfl(sv, 6 + half) * 256];
    for (int i = start; i < end; i += 8) {
        int inext = i + 8;
        int sv_n = ssrc[min(inext + e8, last)];
        int se_n = __shfl(sv_n, h);
        float av_n = as1[se_n * HEADS + e8];
        uint4 n0 = *(const uint4*)&base[(unsigned)__shfl(sv_n, 0 + half) * 256];
        uint4 n1 = *(const uint4*)&base[(unsigned)__shfl(sv_n, 2 + half) * 256];
        uint4 n2 = *(const uint4*)&base[(unsigned)__shfl(sv_n, 4 + half) * 256];
        uint4 n3 = *(const uint4*)&base[(unsigned)__shfl(sv_n, 6 + half) * 256];
        float wv = explrelu(av + ad_w);
        float w0 = __shfl(wv, (0 + half) * 8 + hh);
        float w1 = __shfl(wv, (2 + half) * 8 + hh);
        float w2 = __shfl(wv, (4 + half) * 8 + hh);
        float w3 = __shfl(wv, (6 + half) * 8 + hh);
        w0 = (i + 0 + half < end) ? w0 : 0.f;
        w1 = (i + 2 + half < end) ? w1 : 0.f;
        w2 = (i + 4 + half < end) ? w2 : 0.f;
        w3 = (i + 6 + half < end) ? w3 : 0.f;
        den += w0 + w1 + w2 + w3;
        acc[0] = fmaf(w0, bflo(g0.x), acc[0]); acc[1] = fmaf(w0, bfhi(g0.x), acc[1]);
        acc[2] = fmaf(w0, bflo(g0.y), acc[2]); acc[3] = fmaf(w0, bfhi(g0.y), acc[3]);
        acc[4] = fmaf(w0, bflo(g0.z), acc[4]); acc[5] = fmaf(w0, bfhi(g0.z), acc[5]);
        acc[6] = fmaf(w0, bflo(g0.w), acc[6]); acc[7] = fmaf(w0, bfhi(g0.w), acc[7]);
        acc[0] = fmaf(w1, bflo(g1.x), acc[0]); acc[1] = fmaf(w1, bfhi(g1.x), acc[1]);
        acc[2] = fmaf(w1, bflo(g1.y), acc[2]); acc[3] = fmaf(w1, bfhi(g1.y), acc[3]);
        acc[4] = fmaf(w1, bflo(g1.z), acc[4]); acc[5] = fmaf(w1, bfhi(g1.z), acc[5]);
        acc[6] = fmaf(w1, bflo(g1.w), acc[6]); acc[7] = fmaf(w1, bfhi(g1.w), acc[7]);
        acc[0] = fmaf(w2, bflo(g2.x), acc[0]); acc[1] = fmaf(w2, bfhi(g2.x), acc[1]);
        acc[2] = fmaf(w2, bflo(g2.y), acc[2]); acc[3] = fmaf(w2, bfhi(g2.y), acc[3]);
        acc[4] = fmaf(w2, bflo(g2.z), acc[4]); acc[5] = fmaf(w2, bfhi(g2.z), acc[5]);
        acc[6] = fmaf(w2, bflo(g2.w), acc[6]); acc[7] = fmaf(w2, bfhi(g2.w), acc[7]);
        acc[0] = fmaf(w3, bflo(g3.x), acc[0]); acc[1] = fmaf(w3, bfhi(g3.x), acc[1]);
        acc[2] = fmaf(w3, bflo(g3.y), acc[2]); acc[3] = fmaf(w3, bfhi(g3.y), acc[3]);
        acc[4] = fmaf(w3, bflo(g3.z), acc[4]); acc[5] = fmaf(w3, bfhi(g3.z), acc[5]);
        acc[6] = fmaf(w3, bflo(g3.w), acc[6]); acc[7] = fmaf(w3, bfhi(g3.w), acc[7]);
        g0 = n0; g1 = n1; g2 = n2; g3 = n3;
        sv = sv_n; av = av_n;
    }
#pragma unroll
    for (int j = 0; j < 8; ++j) acc[j] += __shfl_xor(acc[j], 32);
    den += __shfl_xor(den, 32);
    if (lane < 32) {
        float r = __builtin_amdgcn_rcpf(den);
        float4 b0 = *(const float4*)&b1[c * 8];
        float4 b4 = *(const float4*)&b1[c * 8 + 4];
        float v0 = fmaf(acc[0], r, b0.x);
        float v1 = fmaf(acc[1], r, b0.y);
        float v2 = fmaf(acc[2], r, b0.z);
        float v3 = fmaf(acc[3], r, b0.w);
        float v4 = fmaf(acc[4], r, b4.x);
        float v5 = fmaf(acc[5], r, b4.y);
        float v6 = fmaf(acc[6], r, b4.z);
        float v7 = fmaf(acc[7], r, b4.w);
        v0 = v0 > 0.f ? v0 : expm1f(v0);
        v1 = v1 > 0.f ? v1 : expm1f(v1);
        v2 = v2 > 0.f ? v2 : expm1f(v2);
        v3 = v3 > 0.f ? v3 : expm1f(v3);
        v4 = v4 > 0.f ? v4 : expm1f(v4);
        v5 = v5 > 0.f ? v5 : expm1f(v5);
        v6 = v6 > 0.f ? v6 : expm1f(v6);
        v7 = v7 > 0.f ? v7 : expm1f(v7);
        uint4 ob;
        ob.x = (unsigned)f2bf(v0) | ((unsigned)f2bf(v1) << 16);
        ob.y = (unsigned)f2bf(v2) | ((unsigned)f2bf(v3) << 16);
        ob.z = (unsigned)f2bf(v4) | ((unsigned)f2bf(v5) << 16);
        ob.w = (unsigned)f2bf(v6) | ((unsigned)f2bf(v7) << 16);
        *(uint4*)&houtb[(unsigned)n * 256 + c * 8] = ob;
    }
}

// ---------------- GEMM2 via MFMA (bf16 in, fp32 acc) + alpha epilogue -------
__global__ __launch_bounds__(256) void gemm2_mfma(
    const unsigned short* __restrict__ hinb, const unsigned short* __restrict__ W2t,
    const float* __restrict__ att_s2, const float* __restrict__ att_d2,
    unsigned short* __restrict__ h2b, float* __restrict__ as2, float* __restrict__ ad2) {
    int t = threadIdx.x;
    int lane = t & 63;
    int w = t >> 6;
    int lrow = lane & 15;
    int kg = lane >> 4;
    int row0 = blockIdx.x * 64 + w * 16;
    int gr = min(row0 + lrow, N_NODES - 1);    // clamp loads (last block partial)
    f32x4 acc0 = {0.f, 0.f, 0.f, 0.f};
    f32x4 acc1 = {0.f, 0.f, 0.f, 0.f};
    f32x4 acc2 = {0.f, 0.f, 0.f, 0.f};
    f32x4 acc3 = {0.f, 0.f, 0.f, 0.f};
#pragma unroll
    for (int ks = 0; ks < 8; ++ks) {
        int kb = ks * 32 + kg * 8;
        union { bf16x8 v; uint4 u; } A, B0, B1, B2, B3;
        A.u  = *(const uint4*)&hinb[(size_t)gr * 256 + kb];
        B0.u = *(const uint4*)&W2t[(size_t)(0 * 16 + lrow) * 256 + kb];
        B1.u = *(const uint4*)&W2t[(size_t)(1 * 16 + lrow) * 256 + kb];
        B2.u = *(const uint4*)&W2t[(size_t)(2 * 16 + lrow) * 256 + kb];
        B3.u = *(const uint4*)&W2t[(size_t)(3 * 16 + lrow) * 256 + kb];
        acc0 = __builtin_amdgcn_mfma_f32_16x16x32_bf16(A.v, B0.v, acc0, 0, 0, 0);
        acc1 = __builtin_amdgcn_mfma_f32_16x16x32_bf16(A.v, B1.v, acc1, 0, 0, 0);
        acc2 = __builtin_amdgcn_mfma_f32_16x16x32_bf16(A.v, B2.v, acc2, 0, 0, 0);
        acc3 = __builtin_amdgcn_mfma_f32_16x16x32_bf16(A.v, B3.v, acc3, 0, 0, 0);
    }
    float s0 = att_s2[ 0 + lrow], d0 = att_d2[ 0 + lrow];
    float s1 = att_s2[16 + lrow], d1 = att_d2[16 + lrow];
    float s2 = att_s2[32 + lrow], d2 = att_d2[32 + lrow];
    float s3 = att_s2[48 + lrow], d3 = att_d2[48 + lrow];
#pragma unroll
    for (int r = 0; r < 4; ++r) {
        int orow = row0 + kg * 4 + r;
        float p = acc0[r] * s0 + acc1[r] * s1 + acc2[r] * s2 + acc3[r] * s3;
        float q = acc0[r] * d0 + acc1[r] * d1 + acc2[r] * d2 + acc3[r] * d3;
        p += __shfl_xor(p, 1); q += __shfl_xor(q, 1);
        p += __shfl_xor(p, 2); q += __shfl_xor(q, 2);
        p += __shfl_xor(p, 4); q += __shfl_xor(q, 4);
        p += __shfl_xor(p, 8); q += __shfl_xor(q, 8);
        if (orow < N_NODES) {
            h2b[(size_t)orow * 64 +  0 + lrow] = f2bf(acc0[r]);
            h2b[(size_t)orow * 64 + 16 + lrow] = f2bf(acc1[r]);
            h2b[(size_t)orow * 64 + 32 + lrow] = f2bf(acc2[r]);
            h2b[(size_t)orow * 64 + 48 + lrow] = f2bf(acc3[r]);
            if (lrow == 0) { as2[orow] = p; ad2[orow] = q; }
        }
    }
}

// ---------------- Aggregate layer 2: quad-edge wide gathers -----------------
__global__ __launch_bounds__(256) void agg2_kernel(
    const int* __restrict__ off, const int* __restrict__ ssrc,
    const unsigned short* __restrict__ h2b, const float* __restrict__ as2,
    const float* __restrict__ ad2, const float* __restrict__ b2,
    float* __restrict__ out) {
    int t = threadIdx.x;
    int lane = t & 63;
    int e8 = lane & 7;
    int q = lane & 15;
    int quarter = lane >> 4;
    int n = blockIdx.x * 4 + (t >> 6);
    int start = off[n], end = off[n + 1];
    int last = end - 1;
    float adv = ad2[n];
    float acc[4];
#pragma unroll
    for (int j = 0; j < 4; ++j) acc[j] = 0.f;
    float den = 0.f;
    int sv = ssrc[min(start + e8, last)];
    float av = as2[sv];
    for (int i = start; i < end; i += 8) {
        int inext = i + 8;
        int sv_n = ssrc[min(inext + e8, last)];
        float av_n = as2[sv_n];
        float wv = explrelu(av + adv);
#pragma unroll
        for (int k = 0; k < 2; ++k) {
            int me = 4 * k + quarter;
            float wj = __shfl(wv, me);
            int   sj = __shfl(sv, me);
            wj = (i + me < end) ? wj : 0.f;
            uint2 u = *(const uint2*)&h2b[(unsigned)sj * 64 + q * 4];
            den += wj;
            acc[0] = fmaf(wj, bflo(u.x), acc[0]);
            acc[1] = fmaf(wj, bfhi(u.x), acc[1]);
            acc[2] = fmaf(wj, bflo(u.y), acc[2]);
            acc[3] = fmaf(wj, bfhi(u.y), acc[3]);
        }
        sv = sv_n; av = av_n;
    }
#pragma unroll
    for (int j = 0; j < 4; ++j) {
        acc[j] += __shfl_xor(acc[j], 16);
        acc[j] += __shfl_xor(acc[j], 32);
    }
    den += __shfl_xor(den, 16);
    den += __shfl_xor(den, 32);
    if (lane < 16) {
        float r = __builtin_amdgcn_rcpf(den);
        float4 bv = *(const float4*)&b2[q * 4];
        float4 o;
        o.x = fmaf(acc[0], r, bv.x);
        o.y = fmaf(acc[1], r, bv.y);
        o.z = fmaf(acc[2], r, bv.z);
        o.w = fmaf(acc[3], r, bv.w);
        *(float4*)&out[(unsigned)n * 64 + q * 4] = o;
    }
}

extern "C" void kernel_launch(void* const* d_in, const int* in_sizes, int n_in,
                              void* d_out, int out_size, void* d_ws, size_t ws_size,
                              hipStream_t stream) {
    const float* x    = (const float*)d_in[0];
    const int*   ei   = (const int*)d_in[1];
    const float* W1   = (const float*)d_in[2];
    const float* ats1 = (const float*)d_in[3];
    const float* atd1 = (const float*)d_in[4];
    const float* b1   = (const float*)d_in[5];
    const float* W2   = (const float*)d_in[6];
    const float* ats2 = (const float*)d_in[7];
    const float* atd2 = (const float*)d_in[8];
    const float* b2   = (const float*)d_in[9];
    float* out = (float*)d_out;

    char* ws = (char*)d_ws;
    size_t o = 0;
    auto alloc = [&](size_t bytes) { size_t r = o; o = (o + bytes + 255) & ~255UL; return r; };
    unsigned short* h1b   = (unsigned short*)(ws + alloc((size_t)N_NODES * 256 * 2));
    unsigned short* h2inb = (unsigned short*)(ws + alloc((size_t)N_NODES * 256 * 2));
    unsigned short* h2b   = (unsigned short*)(ws + alloc((size_t)N_NODES * 64 * 2));
    unsigned short* W1t   = (unsigned short*)(ws + alloc((size_t)256 * 128 * 2));
    unsigned short* W2t   = (unsigned short*)(ws + alloc((size_t)64 * 256 * 2));
    float* as1  = (float*)(ws + alloc((size_t)N_NODES * HEADS * 4));
    float* ad1  = (float*)(ws + alloc((size_t)N_NODES * HEADS * 4));
    float* as2  = (float*)(ws + alloc((size_t)N_NODES * 4));
    float* ad2  = (float*)(ws + alloc((size_t)N_NODES * 4));
    int*   cnt  = (int*)(ws + alloc((size_t)CNT_TOT * 4));
    int*   pos  = (int*)(ws + alloc((size_t)CNT_TOT * 4));
    int*   bsum = (int*)(ws + alloc(256 * 4));
    int*   off  = (int*)(ws + alloc((size_t)(N_NODES + 1) * 4));
    unsigned int* tmp = (unsigned int*)(ws + alloc((size_t)E_TOT * 4));
    int*   ssrc  = (int*)(ws + alloc((size_t)E_TOT * 4));

    // CSR build (atomic-free) with fused independent work
    fuseA_kernel<<<NCHUNK + 128, 256, 0, stream>>>(ei, cnt, W1, W1t);
    sscan1_kernel<<<SBLK, 256, 0, stream>>>(cnt, pos, bsum);
    sscan2_kernel<<<1, 256, 0, stream>>>(bsum, SBLK);
    fuseB_kernel<<<NCHUNK + G1BLK, 256, 0, stream>>>(
        ei, pos, bsum, tmp, x, W1t, ats1, atd1, h1b, as1, ad1);
    fuseC_kernel<<<NBUCK + 64, 256, 0, stream>>>(pos, bsum, tmp, off, ssrc, W2, W2t);

    // layer 1 aggregate
    agg1_kernel<<<ABLK, 256, 0, stream>>>(off, ssrc, h1b, as1, ad1, b1, h2inb);

    // layer 2
    gemm2_mfma<<<G2BLK, 256, 0, stream>>>(h2inb, W2t, ats2, atd2, h2b, as2, ad2);
    agg2_kernel<<<ABLK, 256, 0, stream>>>(off, ssrc, h2b, as2, ad2, b2, out);
}